// Round 12
// baseline (1137.528 us; speedup 1.0000x reference)
//
#include <hip/hip_runtime.h>

// ---------------------------------------------------------------------------
// CompGCN-style network. MFMA split-bf16 GEMMs.
// Round 12: score GEMM v6b (k_score5, NO inline-asm — r11's asm load pin
// caused a runtime abort; compiler can't track asm loads' vmcnt):
//   - 2-term one-sided split: eh*qh + eh*ql (drop el*q; error ~0.03-0.1,
//     margin to 0.235 threshold remains)
//   - eh-only LDS panel: 28KB -> __launch_bounds__(256,4) -> 4 blocks/CU,
//     16 waves/CU = 2x r10's latency hiding for the per-K-step q reloads
// Rest identical to round 10 (passing, 1087us).
//   N=100000 ents, E=400000 edges, D=200, D0=100, NREL=475, B=1024, L=2
// ---------------------------------------------------------------------------

#define N_ENT  100000
#define N_EDGE 400000
#define D_     200
#define D0_    100
#define NREL_  475
#define B_     1024
#define GSTAT2 2048
#define KP_D   224   // D padded to multiple of 32
#define KP_D0  128   // D0 padded

typedef unsigned short ushort_t;
typedef __attribute__((ext_vector_type(8))) short bf16x8;
typedef __attribute__((ext_vector_type(4))) float f32x4;

__device__ __forceinline__ ushort_t f2bf(float x) {
  unsigned u = __float_as_uint(x);
  return (ushort_t)((u + 0x7FFFu + ((u >> 16) & 1u)) >> 16);
}
__device__ __forceinline__ float bf2f(ushort_t h) {
  return __uint_as_float(((unsigned)h) << 16);
}

__device__ __forceinline__ void gld16(const void* g, void* l) {
  __builtin_amdgcn_global_load_lds(
      (const __attribute__((address_space(1))) unsigned*)g,
      (__attribute__((address_space(3))) unsigned*)l, 16, 0, 0);
}

// ---------------- CSR build (real edges only; self-loops streamed) ----------

__global__ void k_hist(const int* __restrict__ dst_id, int* __restrict__ cnt) {
  int e = blockIdx.x * 256 + threadIdx.x;
  if (e < N_EDGE) atomicAdd(&cnt[dst_id[e]], 1);
}

__global__ __launch_bounds__(256) void k_scan_block(const int* __restrict__ cnt,
                                                    int* __restrict__ rp,
                                                    int* __restrict__ bsum) {
  __shared__ int sm[256];
  int tid = threadIdx.x;
  int base = blockIdx.x * 1024 + tid * 4;
  int v0 = (base + 0 < N_ENT) ? cnt[base + 0] : 0;
  int v1 = (base + 1 < N_ENT) ? cnt[base + 1] : 0;
  int v2 = (base + 2 < N_ENT) ? cnt[base + 2] : 0;
  int v3 = (base + 3 < N_ENT) ? cnt[base + 3] : 0;
  int tsum = v0 + v1 + v2 + v3;
  sm[tid] = tsum;
  __syncthreads();
  for (int off = 1; off < 256; off <<= 1) {
    int t = (tid >= off) ? sm[tid - off] : 0;
    __syncthreads();
    sm[tid] += t;
    __syncthreads();
  }
  int run = sm[tid] - tsum;
  if (base + 0 < N_ENT) { rp[base + 0] = run; } run += v0;
  if (base + 1 < N_ENT) { rp[base + 1] = run; } run += v1;
  if (base + 2 < N_ENT) { rp[base + 2] = run; } run += v2;
  if (base + 3 < N_ENT) { rp[base + 3] = run; }
  if (tid == 255) bsum[blockIdx.x] = sm[255];
}

__global__ void k_scan_tops(int* __restrict__ bsum, int nb) {
  __shared__ int sm[256];
  int tid = threadIdx.x;
  int v = (tid < nb) ? bsum[tid] : 0;
  sm[tid] = v;
  __syncthreads();
  for (int off = 1; off < 256; off <<= 1) {
    int t = (tid >= off) ? sm[tid - off] : 0;
    __syncthreads();
    sm[tid] += t;
    __syncthreads();
  }
  if (tid < nb) bsum[tid] = sm[tid] - v;
}

__global__ void k_scan_add(int* __restrict__ rp, const int* __restrict__ bsum,
                           int* __restrict__ cursor) {
  int i = blockIdx.x * 256 + threadIdx.x;
  if (i < N_ENT) {
    int r = rp[i] + bsum[i >> 10];
    rp[i] = r;
    cursor[i] = r;
  }
}

__global__ void k_fill(const int* __restrict__ src_id, const int* __restrict__ dst_id,
                       const int* __restrict__ e_type, int* __restrict__ cursor,
                       int* __restrict__ cs, int* __restrict__ ct) {
  int e = blockIdx.x * 256 + threadIdx.x;
  if (e < N_EDGE) {
    int pos = atomicAdd(&cursor[dst_id[e]], 1);
    cs[pos] = src_id[e];
    ct[pos] = e_type[e];
  }
}

// ---------------- aggregation / BN ----------------

template <bool BN>
__global__ __launch_bounds__(256) void k_aggregate(const float* __restrict__ ent,
                                                   const float* __restrict__ relE,
                                                   const int* __restrict__ rp,
                                                   const int* __restrict__ cnt,
                                                   const int* __restrict__ cs,
                                                   const int* __restrict__ ct,
                                                   float* __restrict__ out,
                                                   const float* __restrict__ scale,
                                                   const float* __restrict__ shift) {
  int n = blockIdx.x;
  int f = threadIdx.x;
  if (f >= D_) return;
  float sc = 0.f, sh = 0.f;
  if (BN) { sc = scale[f]; sh = shift[f]; }
  float selfE = ent[(long)n * D_ + f];
  if (BN) selfE = fmaxf(fmaf(selfE, sc, sh), 0.f);
  float a0 = selfE * relE[(long)(NREL_ - 1) * D_ + f];
  float a1 = 0.f, a2 = 0.f, a3 = 0.f;
  int s0 = rp[n], e0 = s0 + cnt[n];
  int idx = s0;
  for (; idx + 4 <= e0; idx += 4) {
    int sA = cs[idx + 0], tA = ct[idx + 0];
    int sB = cs[idx + 1], tB = ct[idx + 1];
    int sC = cs[idx + 2], tC = ct[idx + 2];
    int sD = cs[idx + 3], tD = ct[idx + 3];
    float eA = ent[(long)sA * D_ + f], rA = relE[(long)tA * D_ + f];
    float eB = ent[(long)sB * D_ + f], rB = relE[(long)tB * D_ + f];
    float eC = ent[(long)sC * D_ + f], rC = relE[(long)tC * D_ + f];
    float eD = ent[(long)sD * D_ + f], rD = relE[(long)tD * D_ + f];
    if (BN) {
      eA = fmaxf(fmaf(eA, sc, sh), 0.f);
      eB = fmaxf(fmaf(eB, sc, sh), 0.f);
      eC = fmaxf(fmaf(eC, sc, sh), 0.f);
      eD = fmaxf(fmaf(eD, sc, sh), 0.f);
    }
    a0 = fmaf(eA, rA, a0);
    a1 = fmaf(eB, rB, a1);
    a2 = fmaf(eC, rC, a2);
    a3 = fmaf(eD, rD, a3);
  }
  for (; idx < e0; ++idx) {
    int sA = cs[idx], tA = ct[idx];
    float eA = ent[(long)sA * D_ + f];
    if (BN) eA = fmaxf(fmaf(eA, sc, sh), 0.f);
    a0 = fmaf(eA, relE[(long)tA * D_ + f], a0);
  }
  out[(long)n * D_ + f] = (a0 + a1) + (a2 + a3);
}

__global__ __launch_bounds__(64) void k_colstats(const float* __restrict__ X,
                                                 double* __restrict__ part) {
  int t = threadIdx.x;
  if (t >= 50) return;
  double s0 = 0, s1 = 0, s2 = 0, s3 = 0, q0 = 0, q1 = 0, q2 = 0, q3 = 0;
  for (int r = blockIdx.x; r < N_ENT; r += GSTAT2) {
    float4 v = *(const float4*)(X + (long)r * D_ + t * 4);
    s0 += v.x; q0 += (double)v.x * v.x;
    s1 += v.y; q1 += (double)v.y * v.y;
    s2 += v.z; q2 += (double)v.z * v.z;
    s3 += v.w; q3 += (double)v.w * v.w;
  }
  long o = (long)blockIdx.x * 400 + t * 4;
  part[o + 0] = s0; part[o + 1] = s1; part[o + 2] = s2; part[o + 3] = s3;
  part[o + 200] = q0; part[o + 201] = q1; part[o + 202] = q2; part[o + 203] = q3;
}

__global__ __launch_bounds__(256) void k_bn_fin(const double* __restrict__ part,
                                                const float* __restrict__ g,
                                                const float* __restrict__ b,
                                                float* __restrict__ scale,
                                                float* __restrict__ shift) {
  int f = blockIdx.x;  // 0..199
  int tid = threadIdx.x;
  double S = 0.0, S2 = 0.0;
  for (int i = tid; i < GSTAT2; i += 256) {
    S += part[(long)i * 400 + f];
    S2 += part[(long)i * 400 + 200 + f];
  }
  __shared__ double smS[256], smS2[256];
  smS[tid] = S; smS2[tid] = S2;
  __syncthreads();
  for (int off = 128; off > 0; off >>= 1) {
    if (tid < off) { smS[tid] += smS[tid + off]; smS2[tid] += smS2[tid + off]; }
    __syncthreads();
  }
  if (tid == 0) {
    double mean = smS[0] / N_ENT;
    double var = smS2[0] / N_ENT - mean * mean;
    double inv = 1.0 / sqrt(var + 1e-5);
    float sc = g[f] * (float)inv;
    scale[f] = sc;
    shift[f] = b[f] - (float)mean * sc;
  }
}

// BN+ReLU in place AND emit bf16 hi/lo padded split (for score-GEMM B side)
__global__ void k_norm_split(float* __restrict__ X, const float* __restrict__ scale,
                             const float* __restrict__ shift,
                             ushort_t* __restrict__ H, ushort_t* __restrict__ L) {
  const long total = (long)N_ENT * (KP_D / 4);
  for (long i4 = (long)blockIdx.x * 256 + threadIdx.x; i4 < total;
       i4 += (long)gridDim.x * 256) {
    int r = (int)(i4 / (KP_D / 4));
    int c4 = (int)(i4 % (KP_D / 4)) * 4;
    float vv[4] = {0.f, 0.f, 0.f, 0.f};
    if (c4 < D_) {
      float4 v = *(float4*)(X + (long)r * D_ + c4);
      vv[0] = fmaxf(fmaf(v.x, scale[c4 + 0], shift[c4 + 0]), 0.f);
      vv[1] = fmaxf(fmaf(v.y, scale[c4 + 1], shift[c4 + 1]), 0.f);
      vv[2] = fmaxf(fmaf(v.z, scale[c4 + 2], shift[c4 + 2]), 0.f);
      vv[3] = fmaxf(fmaf(v.w, scale[c4 + 3], shift[c4 + 3]), 0.f);
      *(float4*)(X + (long)r * D_ + c4) = make_float4(vv[0], vv[1], vv[2], vv[3]);
    }
    ushort_t h[4], l[4];
#pragma unroll
    for (int t = 0; t < 4; t++) {
      h[t] = f2bf(vv[t]);
      l[t] = f2bf(vv[t] - bf2f(h[t]));
    }
    long o = (long)r * KP_D + c4;
    *(uint2*)(H + o) = make_uint2((unsigned)h[0] | ((unsigned)h[1] << 16),
                                  (unsigned)h[2] | ((unsigned)h[3] << 16));
    *(uint2*)(L + o) = make_uint2((unsigned)l[0] | ((unsigned)l[1] << 16),
                                  (unsigned)l[2] | ((unsigned)l[3] << 16));
  }
}

// W [K][Nc] row-major -> transposed split H/L [Nc][Kp]
__global__ void k_tsplit(const float* __restrict__ W, int K, int Nc, int Kp,
                         ushort_t* __restrict__ H, ushort_t* __restrict__ L) {
  int i = blockIdx.x * 256 + threadIdx.x;
  if (i >= Nc * Kp) return;
  int n = i / Kp, kp = i - n * Kp;
  float v = (kp < K) ? W[(long)kp * Nc + n] : 0.f;
  ushort_t h = f2bf(v);
  H[i] = h;
  L[i] = f2bf(v - bf2f(h));
}

// q[b][kp] = ent[subj[b]][kp] * rel_embed[rel[b]][kp], split hi/lo, padded
__global__ void k_qsplit(const float* __restrict__ ent, const float* __restrict__ relE,
                         const int* __restrict__ subj, const int* __restrict__ rel,
                         ushort_t* __restrict__ H, ushort_t* __restrict__ L) {
  int i = blockIdx.x * 256 + threadIdx.x;
  if (i >= B_ * KP_D) return;
  int b = i / KP_D, kp = i - b * KP_D;
  float v = 0.f;
  if (kp < D_)
    v = ent[(long)subj[b] * D_ + kp] * relE[(long)rel[b] * D_ + kp];
  ushort_t h = f2bf(v);
  H[i] = h;
  L[i] = f2bf(v - bf2f(h));
}

// ---------------- score GEMM v6b: 2-term, eh-only LDS, 4 blocks/CU ----------
// Grid 8 x 1563 (q-chunks x ent panels), XCD-swizzled. Block = 128 q-rows x
// 64 ent-rows; wave owns 32 q-rows x 64 ent-cols.
// ent_h panel only in LDS (28,672 B, swizzled) -> 4 blocks/CU (16 waves).
// One barrier. Terms: eh*qh + eh*ql (el dropped). Plain q loads (no asm).
__global__ __launch_bounds__(256, 4) void k_score5(
    const ushort_t* __restrict__ Ah, const ushort_t* __restrict__ Al,
    const ushort_t* __restrict__ Bh,
    float* __restrict__ C) {
  constexpr int KP = KP_D;  // 224, 7 K-steps
  __shared__ __align__(16) ushort_t lds[14336];  // 28KB: eh panel only
  const int tid = threadIdx.x;
  const int wave = tid >> 6, lane = tid & 63;
  const int l15 = lane & 15, l4 = lane >> 4;

  int g = (blockIdx.x & 7) * 1563 + (blockIdx.x >> 3);
  const int bm = (g & 7) * 128;       // q chunk (8 of 128)
  const int bn = (g >> 3) * 64;       // ent panel

  // ---- q loads (compiler-scheduled; 16 waves/CU hide the L2 latency) ----
  bf16x8 qh[2][7], ql[2][7];
#pragma unroll
  for (int i = 0; i < 2; ++i) {
    long rowa = (long)(bm + wave * 32 + i * 16 + l15) * KP + l4 * 8;
#pragma unroll
    for (int k = 0; k < 7; ++k) {
      qh[i][k] = *(const bf16x8*)(Ah + rowa + k * 32);
      ql[i][k] = *(const bf16x8*)(Al + rowa + k * 32);
    }
  }

  // ---- stage ent_h panel once (28 chunks x 1KB, swizzled slots) ----
#pragma unroll
  for (int jj = 0; jj < 7; ++jj) {
    int c = wave * 7 + jj;
    int u = c * 64 + lane;              // 16B-unit index, [0,1792)
    int kst = u >> 8;
    int rem = u & 255;
    int r = rem >> 2;
    int slot = rem & 3;
    int srcslot = slot ^ ((r >> 1) & 3);
    int rowg = bn + r; if (rowg > N_ENT - 1) rowg = N_ENT - 1;
    gld16(Bh + (long)rowg * KP + kst * 32 + srcslot * 8, lds + c * 512);
  }
  __syncthreads();

  // ---- compute: mfma(eh, qh) + mfma(eh, ql)  (2 terms) ----
  f32x4 acc[2][4] = {};   // [iq][je]
#pragma unroll
  for (int k = 0; k < 7; ++k) {
    bf16x8 eh[4];
#pragma unroll
    for (int j = 0; j < 4; ++j) {
      int rB = j * 16 + l15;
      int slot = l4 ^ ((rB >> 1) & 3);
      eh[j] = *(const bf16x8*)(lds + k * 2048 + rB * 32 + slot * 8);
    }
#pragma unroll
    for (int i = 0; i < 2; ++i)
#pragma unroll
      for (int j = 0; j < 4; ++j) {
        acc[i][j] = __builtin_amdgcn_mfma_f32_16x16x32_bf16(eh[j], qh[i][k], acc[i][j], 0, 0, 0);
        acc[i][j] = __builtin_amdgcn_mfma_f32_16x16x32_bf16(eh[j], ql[i][k], acc[i][j], 0, 0, 0);
      }
  }

  // ---- store: lane holds 4 consecutive ent columns -> float4 ----
#pragma unroll
  for (int i = 0; i < 2; ++i) {
    int m = bm + wave * 32 + i * 16 + l15;   // q row = D col = lane&15
#pragma unroll
    for (int j = 0; j < 4; ++j) {
      int nb = bn + j * 16 + l4 * 4;         // ent rows = D rows = l4*4+v
      if (nb < N_ENT) {
        float4 o = make_float4(acc[i][j][0], acc[i][j][1], acc[i][j][2], acc[i][j][3]);
        *(float4*)(C + (long)m * N_ENT + nb) = o;
      }
    }
  }
}

// ---------------- MFMA GEMM, f32 A with fused (BN+ReLU+)split (concat/init) ----
template <bool BN_A, bool HAS_BIAS>
__global__ __launch_bounds__(256, 2) void k_mfma_af32(
    const float* __restrict__ A, int lda, int K,
    const ushort_t* __restrict__ Bh, const ushort_t* __restrict__ Bl,
    float* __restrict__ C, int M, int Nc, int Kp, long ldc,
    const float* __restrict__ scale, const float* __restrict__ shift,
    const float* __restrict__ bias) {
  __shared__ __align__(16) ushort_t lds[2 * 16384];
  __shared__ float sc_lds[KP_D], sh_lds[KP_D];
  const int tid = threadIdx.x;
  const int wave = tid >> 6, lane = tid & 63;
  const int bm = blockIdx.x * 128, bn = blockIdx.y * 128;
  const int wr = (wave >> 1) * 64, wc = (wave & 1) * 64;
  const int l15 = lane & 15, l4 = lane >> 4;
  const int NT = Kp >> 5;

  if (BN_A) {
    for (int i = tid; i < Kp; i += 256) {
      sc_lds[i] = (i < K) ? scale[i] : 0.f;
      sh_lds[i] = (i < K) ? shift[i] : 0.f;
    }
    __syncthreads();
  }

  const int ar = tid >> 1;
  const int acb = (tid & 1) * 16;
  int arow = bm + ar; if (arow > M - 1) arow = M - 1;
  const int aswz = (ar >> 1) & 3;
  const int s0 = (((acb >> 3) + 0) ^ aswz) * 8;
  const int s1 = (((acb >> 3) + 1) ^ aswz) * 8;

  auto loadA = [&](int kt, float4* va) {
    int kc = kt * 32 + acb;
    const float* ap = A + (long)arow * lda + kc;
    if (kc + 16 <= K) {
#pragma unroll
      for (int q = 0; q < 4; q++) va[q] = *(const float4*)(ap + q * 4);
    } else {
#pragma unroll
      for (int q = 0; q < 4; q++) {
        float t0 = (kc + q * 4 + 0 < K) ? ap[q * 4 + 0] : 0.f;
        float t1 = (kc + q * 4 + 1 < K) ? ap[q * 4 + 1] : 0.f;
        float t2 = (kc + q * 4 + 2 < K) ? ap[q * 4 + 2] : 0.f;
        float t3 = (kc + q * 4 + 3 < K) ? ap[q * 4 + 3] : 0.f;
        va[q] = make_float4(t0, t1, t2, t3);
      }
    }
  };

  auto writeA = [&](int kt, int ph, float4* va) {
    float v[16];
#pragma unroll
    for (int q = 0; q < 4; q++) {
      v[q * 4 + 0] = va[q].x; v[q * 4 + 1] = va[q].y;
      v[q * 4 + 2] = va[q].z; v[q * 4 + 3] = va[q].w;
    }
    if (BN_A) {
      int kc = kt * 32 + acb;
#pragma unroll
      for (int e = 0; e < 16; e++) {
        int col = kc + e;
        if (col < K) v[e] = fmaxf(fmaf(v[e], sc_lds[col], sh_lds[col]), 0.f);
      }
    }
    unsigned hh[8], ll[8];
#pragma unroll
    for (int e = 0; e < 8; e++) {
      ushort_t h0 = f2bf(v[2 * e]), h1 = f2bf(v[2 * e + 1]);
      ushort_t l0 = f2bf(v[2 * e] - bf2f(h0)), l1 = f2bf(v[2 * e + 1] - bf2f(h1));
      hh[e] = (unsigned)h0 | ((unsigned)h1 << 16);
      ll[e] = (unsigned)l0 | ((unsigned)l1 << 16);
    }
    ushort_t* baseA = lds + ph * 16384 + ar * 32;
    *(uint4*)(baseA + s0) = make_uint4(hh[0], hh[1], hh[2], hh[3]);
    *(uint4*)(baseA + s1) = make_uint4(hh[4], hh[5], hh[6], hh[7]);
    ushort_t* baseL = baseA + 4096;
    *(uint4*)(baseL + s0) = make_uint4(ll[0], ll[1], ll[2], ll[3]);
    *(uint4*)(baseL + s1) = make_uint4(ll[4], ll[5], ll[6], ll[7]);
  };

  auto stageB = [&](int kt, int ph) {
#pragma unroll
    for (int j = 0; j < 4; ++j) {
      int c = 16 + wave * 4 + j;
      int buf = c >> 3;
      int r = (c & 7) * 16 + (lane >> 2);
      int sg = (lane & 3) ^ ((r >> 1) & 3);
      const ushort_t* bp = (buf == 2) ? Bh : Bl;
      int rowg = bn + r; if (rowg > Nc - 1) rowg = Nc - 1;
      gld16(bp + (long)rowg * Kp + kt * 32 + sg * 8, lds + ph * 16384 + c * 512);
    }
  };

  f32x4 acc[4][4] = {};
  {
    float4 va[4];
    loadA(0, va);
    writeA(0, 0, va);
    stageB(0, 0);
  }
  __syncthreads();
  int p = 0;
  for (int t = 0; t < NT; ++t) {
    float4 va[4];
    const bool pre = (t + 1 < NT);
    if (pre) {
      loadA(t + 1, va);
      stageB(t + 1, p ^ 1);
    }
    const ushort_t* base = lds + p * 16384;
    bf16x8 a_h[4], a_l[4], b_h[4], b_l[4];
#pragma unroll
    for (int i = 0; i < 4; i++) {
      int rA = wr + i * 16 + l15;
      int sA = (l4 ^ ((rA >> 1) & 3)) * 8;
      a_h[i] = *(const bf16x8*)(base + rA * 32 + sA);
      a_l[i] = *(const bf16x8*)(base + 4096 + rA * 32 + sA);
      int rB = wc + i * 16 + l15;
      int sB = (l4 ^ ((rB >> 1) & 3)) * 8;
      b_h[i] = *(const bf16x8*)(base + 8192 + rB * 32 + sB);
      b_l[i] = *(const bf16x8*)(base + 12288 + rB * 32 + sB);
    }
#pragma unroll
    for (int i = 0; i < 4; i++)
#pragma unroll
      for (int j = 0; j < 4; j++) {
        acc[i][j] = __builtin_amdgcn_mfma_f32_16x16x32_bf16(a_h[i], b_h[j], acc[i][j], 0, 0, 0);
        acc[i][j] = __builtin_amdgcn_mfma_f32_16x16x32_bf16(a_l[i], b_h[j], acc[i][j], 0, 0, 0);
        acc[i][j] = __builtin_amdgcn_mfma_f32_16x16x32_bf16(a_h[i], b_l[j], acc[i][j], 0, 0, 0);
      }
    if (pre) writeA(t + 1, p ^ 1, va);
    __syncthreads();
    p ^= 1;
  }

#pragma unroll
  for (int i = 0; i < 4; i++) {
    int mrow = bm + wr + i * 16 + l4 * 4;
#pragma unroll
    for (int j = 0; j < 4; j++) {
      int n = bn + wc + j * 16 + l15;
      if (n >= Nc) continue;
      float bb = HAS_BIAS ? bias[n] : 0.f;
#pragma unroll
      for (int v = 0; v < 4; v++) {
        int m = mrow + v;
        if (m < M) C[(long)m * ldc + n] = acc[i][j][v] + bb;
      }
    }
  }
}

// ---------------- small f32 GEMM (tiny rel transforms) ----------------
template <int TM, int TN>
__global__ __launch_bounds__(256) void k_gemm_abt(
    const float* __restrict__ A, const float* __restrict__ Bm, float* __restrict__ C,
    int M, int Nc, int K, long ldc) {
  constexpr int BM = TM * 16, BN = TN * 16, KC = 20;
  __shared__ float As[BM * KC];
  __shared__ float Bs[BN * KC];
  const int tid = threadIdx.x;
  const int tx = tid & 15, ty = tid >> 4;
  const int bm = blockIdx.x * BM, bn = blockIdx.y * BN;
  float acc[TM][TN];
#pragma unroll
  for (int i = 0; i < TM; i++)
#pragma unroll
    for (int j = 0; j < TN; j++) acc[i][j] = 0.f;
  for (int kc = 0; kc < K; kc += KC) {
    for (int i4 = tid; i4 < BM * 5; i4 += 256) {
      int r = i4 / 5, kq = (i4 - r * 5) * 4;
      int row = bm + r; if (row > M - 1) row = M - 1;
      *(float4*)(As + r * KC + kq) = *(const float4*)(A + (long)row * K + kc + kq);
    }
    for (int i4 = tid; i4 < BN * 5; i4 += 256) {
      int r = i4 / 5, kq = (i4 - r * 5) * 4;
      int row = bn + r; if (row > Nc - 1) row = Nc - 1;
      *(float4*)(Bs + r * KC + kq) = *(const float4*)(Bm + (long)row * K + kc + kq);
    }
    __syncthreads();
#pragma unroll
    for (int k4 = 0; k4 < KC; k4 += 4) {
      float4 af[TM], bf[TN];
#pragma unroll
      for (int i = 0; i < TM; i++) af[i] = *(const float4*)(As + (i * 16 + ty) * KC + k4);
#pragma unroll
      for (int j = 0; j < TN; j++) bf[j] = *(const float4*)(Bs + (j * 16 + tx) * KC + k4);
#pragma unroll
      for (int i = 0; i < TM; i++)
#pragma unroll
        for (int j = 0; j < TN; j++) {
          acc[i][j] = fmaf(af[i].x, bf[j].x, acc[i][j]);
          acc[i][j] = fmaf(af[i].y, bf[j].y, acc[i][j]);
          acc[i][j] = fmaf(af[i].z, bf[j].z, acc[i][j]);
          acc[i][j] = fmaf(af[i].w, bf[j].w, acc[i][j]);
        }
    }
    __syncthreads();
  }
#pragma unroll
  for (int i = 0; i < TM; i++) {
    int m = bm + i * 16 + ty;
    if (m >= M) continue;
#pragma unroll
    for (int j = 0; j < TN; j++) {
      int n = bn + j * 16 + tx;
      if (n < Nc) C[(long)m * ldc + n] = acc[i][j];
    }
  }
}

__global__ void k_transpose(const float* __restrict__ s, float* __restrict__ d, int R, int C) {
  int i = blockIdx.x * 256 + threadIdx.x;
  if (i < R * C) { int r = i / C, c = i - r * C; d[c * R + r] = s[i]; }
}

// ---------------------------------------------------------------------------

extern "C" void kernel_launch(void* const* d_in, const int* in_sizes, int n_in,
                              void* d_out, int out_size, void* d_ws, size_t ws_size,
                              hipStream_t stream) {
  const int* src_id = (const int*)d_in[0];
  const int* dst_id = (const int*)d_in[1];
  const int* e_type = (const int*)d_in[2];
  const int* subj = (const int*)d_in[3];
  const int* rel = (const int*)d_in[4];
  const float* emb_h = (const float*)d_in[5];
  const float* emb_e = (const float*)d_in[6];
  const float* lin_w = (const float*)d_in[7];
  const float* lin_b = (const float*)d_in[8];
  const float* rel_wt = (const float*)d_in[9];
  const float* w_rel = (const float*)d_in[10];
  const float* agg_bn_g = (const float*)d_in[11];
  const float* agg_bn_b = (const float*)d_in[12];
  const float* cell_bn_g = (const float*)d_in[13];
  const float* cell_bn_b = (const float*)d_in[14];
  const float* concat_w = (const float*)d_in[15];
  const float* concat_b = (const float*)d_in[16];
  float* out = (float*)d_out;

  // ---- d_ws: only score-GEMM operands (read while d_out is written) ----
  char* w = (char*)d_ws;
  ushort_t* ent_h = (ushort_t*)(w + 0);           // 44,800,000
  ushort_t* ent_l = (ushort_t*)(w + 44800000);    // 44,800,000 (written, unused by score)
  ushort_t* q_h   = (ushort_t*)(w + 89600000);    //    458,752
  ushort_t* q_l   = (ushort_t*)(w + 90112000);    //    458,752

  // ---- d_out front as temp (all dead before score GEMM) ----
  char* ob = (char*)d_out;
  float* ent    = (float*)(ob + 0);             // 80,000,000
  float* tmp    = (float*)(ob + 80000000);      // 80,000,000
  double* part  = (double*)(ob + 160000000);    //  6,553,600
  int* counts   = (int*)(ob + 166600000);       //    400,000
  int* row_ptr  = (int*)(ob + 167000000);
  int* cursor   = (int*)(ob + 167400000);
  int* csr_src  = (int*)(ob + 167800000);       //  1,600,000
  int* csr_et   = (int*)(ob + 169400000);       //  1,600,000
  float* relA   = (float*)(ob + 171800000);     //    380,000
  float* relB   = (float*)(ob + 172180000);     //    380,000
  float* embeT  = (float*)(ob + 172560000);     //     80,000
  float* wrT    = (float*)(ob + 172640000);     //    160,000
  ushort_t* linw_h = (ushort_t*)(ob + 172800000);  // 51,200
  ushort_t* linw_l = (ushort_t*)(ob + 172851200);  // 51,200
  ushort_t* cw0_h  = (ushort_t*)(ob + 172902400);  // 89,600
  ushort_t* cw0_l  = (ushort_t*)(ob + 172992000);
  ushort_t* cw1_h  = (ushort_t*)(ob + 173081600);
  ushort_t* cw1_l  = (ushort_t*)(ob + 173171200);
  float* scaleb = (float*)(ob + 173260800);     // 1,024
  float* shiftb = (float*)(ob + 173261824);     // 1,024
  int* bsum     = (int*)(ob + 173262848);       //   512

  // ---- CSR build (real edges only) ----
  hipMemsetAsync(counts, 0, N_ENT * sizeof(int), stream);
  k_hist<<<(N_EDGE + 255) / 256, 256, 0, stream>>>(dst_id, counts);
  const int NB = (N_ENT + 1023) / 1024;  // 98
  k_scan_block<<<NB, 256, 0, stream>>>(counts, row_ptr, bsum);
  k_scan_tops<<<1, 256, 0, stream>>>(bsum, NB);
  k_scan_add<<<(N_ENT + 255) / 256, 256, 0, stream>>>(row_ptr, bsum, cursor);
  k_fill<<<(N_EDGE + 255) / 256, 256, 0, stream>>>(src_id, dst_id, e_type, cursor,
                                                   csr_src, csr_et);

  // ---- weight prep ----
  k_tsplit<<<(D_ * KP_D0 + 255) / 256, 256, 0, stream>>>(lin_w, D0_, D_, KP_D0,
                                                         linw_h, linw_l);
  k_tsplit<<<(D_ * KP_D + 255) / 256, 256, 0, stream>>>(concat_w, D_, D_, KP_D,
                                                        cw0_h, cw0_l);
  k_tsplit<<<(D_ * KP_D + 255) / 256, 256, 0, stream>>>(concat_w + D_ * D_, D_, D_,
                                                        KP_D, cw1_h, cw1_l);
  k_transpose<<<(D0_ * D_ + 255) / 256, 256, 0, stream>>>(emb_e, embeT, D0_, D_);
  k_transpose<<<(D_ * D_ + 255) / 256, 256, 0, stream>>>(w_rel, wrT, D_, D_);

  const int GM = (N_ENT + 127) / 128;  // 782

  // ---- init projections (A = emb_h f32, fused split in-kernel) ----
  k_mfma_af32<false, true><<<dim3(GM, 2), 256, 0, stream>>>(
      emb_h, D0_, D0_, linw_h, linw_l, ent, N_ENT, D_, KP_D0, (long)D_,
      nullptr, nullptr, lin_b);
  k_gemm_abt<8, 4><<<dim3(4, 4), 256, 0, stream>>>(rel_wt, embeT, relA, NREL_, D_,
                                                   D0_, (long)D_);

  // ================= layer 0 =================
  k_aggregate<false><<<N_ENT, 256, 0, stream>>>(ent, relA, row_ptr, counts,
                                                csr_src, csr_et, tmp, nullptr, nullptr);
  k_colstats<<<GSTAT2, 64, 0, stream>>>(tmp, part);
  k_bn_fin<<<D_, 256, 0, stream>>>(part, agg_bn_g, agg_bn_b, scaleb, shiftb);
  k_mfma_af32<true, true><<<dim3(GM, 2), 256, 0, stream>>>(
      tmp, D_, D_, cw0_h, cw0_l, ent, N_ENT, D_, KP_D, (long)D_,
      scaleb, shiftb, concat_b);
  k_colstats<<<GSTAT2, 64, 0, stream>>>(ent, part);
  k_bn_fin<<<D_, 256, 0, stream>>>(part, cell_bn_g, cell_bn_b, scaleb, shiftb);
  // cell-BN0 not materialized: fused into layer-1 aggregate's gather
  k_gemm_abt<8, 4><<<dim3(4, 4), 256, 0, stream>>>(relA, wrT, relB, NREL_, D_, D_,
                                                   (long)D_);

  // ================= layer 1 =================
  k_aggregate<true><<<N_ENT, 256, 0, stream>>>(ent, relB, row_ptr, counts,
                                               csr_src, csr_et, tmp, scaleb, shiftb);
  k_colstats<<<GSTAT2, 64, 0, stream>>>(tmp, part);
  k_bn_fin<<<D_, 256, 0, stream>>>(part, agg_bn_g + D_, agg_bn_b + D_, scaleb, shiftb);
  k_mfma_af32<true, true><<<dim3(GM, 2), 256, 0, stream>>>(
      tmp, D_, D_, cw1_h, cw1_l, ent, N_ENT, D_, KP_D, (long)D_,
      scaleb, shiftb, concat_b + D_);
  k_colstats<<<GSTAT2, 64, 0, stream>>>(ent, part);
  k_bn_fin<<<D_, 256, 0, stream>>>(part, cell_bn_g + D_, cell_bn_b + D_, scaleb, shiftb);
  k_norm_split<<<2048, 256, 0, stream>>>(ent, scaleb, shiftb, ent_h, ent_l);
  k_gemm_abt<8, 4><<<dim3(4, 4), 256, 0, stream>>>(relB, wrT, relA, NREL_, D_, D_,
                                                   (long)D_);

  // ---- score operands ----
  k_qsplit<<<(B_ * KP_D + 255) / 256, 256, 0, stream>>>(ent, relA, subj, rel,
                                                        q_h, q_l);

  // ---- DistMult score: 2-term, eh-only LDS, 4 blocks/CU ----
  k_score5<<<dim3(8 * 1563), 256, 0, stream>>>(q_h, q_l, ent_h, out);
}

// Round 14
// 1133.086 us; speedup vs baseline: 1.0039x; 1.0039x over previous
//
#include <hip/hip_runtime.h>

// ---------------------------------------------------------------------------
// CompGCN-style network. MFMA split-bf16 GEMMs.
// Round 14: = round 13 with the compile fix: __builtin_nontemporal_store
// takes the clang ext-vector f32x4 (HIP float4 struct rejected).
//   Score GEMM v6c: 2-term (eh*qh + eh*ql), eh-only 28KB LDS (4 blocks/CU),
//   NON-TEMPORAL C stores (r12 showed 4MB dirty-C/XCD == L2 -> 1.75x write
//   amplification + ent evictions; nt bypasses L2, full 64B sectors).
// Rest identical to round 12 (passing, absmax 0.0625).
//   N=100000 ents, E=400000 edges, D=200, D0=100, NREL=475, B=1024, L=2
// ---------------------------------------------------------------------------

#define N_ENT  100000
#define N_EDGE 400000
#define D_     200
#define D0_    100
#define NREL_  475
#define B_     1024
#define GSTAT2 2048
#define KP_D   224   // D padded to multiple of 32
#define KP_D0  128   // D0 padded

typedef unsigned short ushort_t;
typedef __attribute__((ext_vector_type(8))) short bf16x8;
typedef __attribute__((ext_vector_type(4))) float f32x4;

__device__ __forceinline__ ushort_t f2bf(float x) {
  unsigned u = __float_as_uint(x);
  return (ushort_t)((u + 0x7FFFu + ((u >> 16) & 1u)) >> 16);
}
__device__ __forceinline__ float bf2f(ushort_t h) {
  return __uint_as_float(((unsigned)h) << 16);
}

__device__ __forceinline__ void gld16(const void* g, void* l) {
  __builtin_amdgcn_global_load_lds(
      (const __attribute__((address_space(1))) unsigned*)g,
      (__attribute__((address_space(3))) unsigned*)l, 16, 0, 0);
}

// ---------------- CSR build (real edges only; self-loops streamed) ----------

__global__ void k_hist(const int* __restrict__ dst_id, int* __restrict__ cnt) {
  int e = blockIdx.x * 256 + threadIdx.x;
  if (e < N_EDGE) atomicAdd(&cnt[dst_id[e]], 1);
}

__global__ __launch_bounds__(256) void k_scan_block(const int* __restrict__ cnt,
                                                    int* __restrict__ rp,
                                                    int* __restrict__ bsum) {
  __shared__ int sm[256];
  int tid = threadIdx.x;
  int base = blockIdx.x * 1024 + tid * 4;
  int v0 = (base + 0 < N_ENT) ? cnt[base + 0] : 0;
  int v1 = (base + 1 < N_ENT) ? cnt[base + 1] : 0;
  int v2 = (base + 2 < N_ENT) ? cnt[base + 2] : 0;
  int v3 = (base + 3 < N_ENT) ? cnt[base + 3] : 0;
  int tsum = v0 + v1 + v2 + v3;
  sm[tid] = tsum;
  __syncthreads();
  for (int off = 1; off < 256; off <<= 1) {
    int t = (tid >= off) ? sm[tid - off] : 0;
    __syncthreads();
    sm[tid] += t;
    __syncthreads();
  }
  int run = sm[tid] - tsum;
  if (base + 0 < N_ENT) { rp[base + 0] = run; } run += v0;
  if (base + 1 < N_ENT) { rp[base + 1] = run; } run += v1;
  if (base + 2 < N_ENT) { rp[base + 2] = run; } run += v2;
  if (base + 3 < N_ENT) { rp[base + 3] = run; }
  if (tid == 255) bsum[blockIdx.x] = sm[255];
}

__global__ void k_scan_tops(int* __restrict__ bsum, int nb) {
  __shared__ int sm[256];
  int tid = threadIdx.x;
  int v = (tid < nb) ? bsum[tid] : 0;
  sm[tid] = v;
  __syncthreads();
  for (int off = 1; off < 256; off <<= 1) {
    int t = (tid >= off) ? sm[tid - off] : 0;
    __syncthreads();
    sm[tid] += t;
    __syncthreads();
  }
  if (tid < nb) bsum[tid] = sm[tid] - v;
}

__global__ void k_scan_add(int* __restrict__ rp, const int* __restrict__ bsum,
                           int* __restrict__ cursor) {
  int i = blockIdx.x * 256 + threadIdx.x;
  if (i < N_ENT) {
    int r = rp[i] + bsum[i >> 10];
    rp[i] = r;
    cursor[i] = r;
  }
}

__global__ void k_fill(const int* __restrict__ src_id, const int* __restrict__ dst_id,
                       const int* __restrict__ e_type, int* __restrict__ cursor,
                       int* __restrict__ cs, int* __restrict__ ct) {
  int e = blockIdx.x * 256 + threadIdx.x;
  if (e < N_EDGE) {
    int pos = atomicAdd(&cursor[dst_id[e]], 1);
    cs[pos] = src_id[e];
    ct[pos] = e_type[e];
  }
}

// ---------------- aggregation / BN ----------------

template <bool BN>
__global__ __launch_bounds__(256) void k_aggregate(const float* __restrict__ ent,
                                                   const float* __restrict__ relE,
                                                   const int* __restrict__ rp,
                                                   const int* __restrict__ cnt,
                                                   const int* __restrict__ cs,
                                                   const int* __restrict__ ct,
                                                   float* __restrict__ out,
                                                   const float* __restrict__ scale,
                                                   const float* __restrict__ shift) {
  int n = blockIdx.x;
  int f = threadIdx.x;
  if (f >= D_) return;
  float sc = 0.f, sh = 0.f;
  if (BN) { sc = scale[f]; sh = shift[f]; }
  float selfE = ent[(long)n * D_ + f];
  if (BN) selfE = fmaxf(fmaf(selfE, sc, sh), 0.f);
  float a0 = selfE * relE[(long)(NREL_ - 1) * D_ + f];
  float a1 = 0.f, a2 = 0.f, a3 = 0.f;
  int s0 = rp[n], e0 = s0 + cnt[n];
  int idx = s0;
  for (; idx + 4 <= e0; idx += 4) {
    int sA = cs[idx + 0], tA = ct[idx + 0];
    int sB = cs[idx + 1], tB = ct[idx + 1];
    int sC = cs[idx + 2], tC = ct[idx + 2];
    int sD = cs[idx + 3], tD = ct[idx + 3];
    float eA = ent[(long)sA * D_ + f], rA = relE[(long)tA * D_ + f];
    float eB = ent[(long)sB * D_ + f], rB = relE[(long)tB * D_ + f];
    float eC = ent[(long)sC * D_ + f], rC = relE[(long)tC * D_ + f];
    float eD = ent[(long)sD * D_ + f], rD = relE[(long)tD * D_ + f];
    if (BN) {
      eA = fmaxf(fmaf(eA, sc, sh), 0.f);
      eB = fmaxf(fmaf(eB, sc, sh), 0.f);
      eC = fmaxf(fmaf(eC, sc, sh), 0.f);
      eD = fmaxf(fmaf(eD, sc, sh), 0.f);
    }
    a0 = fmaf(eA, rA, a0);
    a1 = fmaf(eB, rB, a1);
    a2 = fmaf(eC, rC, a2);
    a3 = fmaf(eD, rD, a3);
  }
  for (; idx < e0; ++idx) {
    int sA = cs[idx], tA = ct[idx];
    float eA = ent[(long)sA * D_ + f];
    if (BN) eA = fmaxf(fmaf(eA, sc, sh), 0.f);
    a0 = fmaf(eA, relE[(long)tA * D_ + f], a0);
  }
  out[(long)n * D_ + f] = (a0 + a1) + (a2 + a3);
}

__global__ __launch_bounds__(64) void k_colstats(const float* __restrict__ X,
                                                 double* __restrict__ part) {
  int t = threadIdx.x;
  if (t >= 50) return;
  double s0 = 0, s1 = 0, s2 = 0, s3 = 0, q0 = 0, q1 = 0, q2 = 0, q3 = 0;
  for (int r = blockIdx.x; r < N_ENT; r += GSTAT2) {
    float4 v = *(const float4*)(X + (long)r * D_ + t * 4);
    s0 += v.x; q0 += (double)v.x * v.x;
    s1 += v.y; q1 += (double)v.y * v.y;
    s2 += v.z; q2 += (double)v.z * v.z;
    s3 += v.w; q3 += (double)v.w * v.w;
  }
  long o = (long)blockIdx.x * 400 + t * 4;
  part[o + 0] = s0; part[o + 1] = s1; part[o + 2] = s2; part[o + 3] = s3;
  part[o + 200] = q0; part[o + 201] = q1; part[o + 202] = q2; part[o + 203] = q3;
}

__global__ __launch_bounds__(256) void k_bn_fin(const double* __restrict__ part,
                                                const float* __restrict__ g,
                                                const float* __restrict__ b,
                                                float* __restrict__ scale,
                                                float* __restrict__ shift) {
  int f = blockIdx.x;  // 0..199
  int tid = threadIdx.x;
  double S = 0.0, S2 = 0.0;
  for (int i = tid; i < GSTAT2; i += 256) {
    S += part[(long)i * 400 + f];
    S2 += part[(long)i * 400 + 200 + f];
  }
  __shared__ double smS[256], smS2[256];
  smS[tid] = S; smS2[tid] = S2;
  __syncthreads();
  for (int off = 128; off > 0; off >>= 1) {
    if (tid < off) { smS[tid] += smS[tid + off]; smS2[tid] += smS2[tid + off]; }
    __syncthreads();
  }
  if (tid == 0) {
    double mean = smS[0] / N_ENT;
    double var = smS2[0] / N_ENT - mean * mean;
    double inv = 1.0 / sqrt(var + 1e-5);
    float sc = g[f] * (float)inv;
    scale[f] = sc;
    shift[f] = b[f] - (float)mean * sc;
  }
}

// BN+ReLU in place AND emit bf16 hi/lo padded split (for score-GEMM B side)
__global__ void k_norm_split(float* __restrict__ X, const float* __restrict__ scale,
                             const float* __restrict__ shift,
                             ushort_t* __restrict__ H, ushort_t* __restrict__ L) {
  const long total = (long)N_ENT * (KP_D / 4);
  for (long i4 = (long)blockIdx.x * 256 + threadIdx.x; i4 < total;
       i4 += (long)gridDim.x * 256) {
    int r = (int)(i4 / (KP_D / 4));
    int c4 = (int)(i4 % (KP_D / 4)) * 4;
    float vv[4] = {0.f, 0.f, 0.f, 0.f};
    if (c4 < D_) {
      float4 v = *(float4*)(X + (long)r * D_ + c4);
      vv[0] = fmaxf(fmaf(v.x, scale[c4 + 0], shift[c4 + 0]), 0.f);
      vv[1] = fmaxf(fmaf(v.y, scale[c4 + 1], shift[c4 + 1]), 0.f);
      vv[2] = fmaxf(fmaf(v.z, scale[c4 + 2], shift[c4 + 2]), 0.f);
      vv[3] = fmaxf(fmaf(v.w, scale[c4 + 3], shift[c4 + 3]), 0.f);
      *(float4*)(X + (long)r * D_ + c4) = make_float4(vv[0], vv[1], vv[2], vv[3]);
    }
    ushort_t h[4], l[4];
#pragma unroll
    for (int t = 0; t < 4; t++) {
      h[t] = f2bf(vv[t]);
      l[t] = f2bf(vv[t] - bf2f(h[t]));
    }
    long o = (long)r * KP_D + c4;
    *(uint2*)(H + o) = make_uint2((unsigned)h[0] | ((unsigned)h[1] << 16),
                                  (unsigned)h[2] | ((unsigned)h[3] << 16));
    *(uint2*)(L + o) = make_uint2((unsigned)l[0] | ((unsigned)l[1] << 16),
                                  (unsigned)l[2] | ((unsigned)l[3] << 16));
  }
}

// W [K][Nc] row-major -> transposed split H/L [Nc][Kp]
__global__ void k_tsplit(const float* __restrict__ W, int K, int Nc, int Kp,
                         ushort_t* __restrict__ H, ushort_t* __restrict__ L) {
  int i = blockIdx.x * 256 + threadIdx.x;
  if (i >= Nc * Kp) return;
  int n = i / Kp, kp = i - n * Kp;
  float v = (kp < K) ? W[(long)kp * Nc + n] : 0.f;
  ushort_t h = f2bf(v);
  H[i] = h;
  L[i] = f2bf(v - bf2f(h));
}

// q[b][kp] = ent[subj[b]][kp] * rel_embed[rel[b]][kp], split hi/lo, padded
__global__ void k_qsplit(const float* __restrict__ ent, const float* __restrict__ relE,
                         const int* __restrict__ subj, const int* __restrict__ rel,
                         ushort_t* __restrict__ H, ushort_t* __restrict__ L) {
  int i = blockIdx.x * 256 + threadIdx.x;
  if (i >= B_ * KP_D) return;
  int b = i / KP_D, kp = i - b * KP_D;
  float v = 0.f;
  if (kp < D_)
    v = ent[(long)subj[b] * D_ + kp] * relE[(long)rel[b] * D_ + kp];
  ushort_t h = f2bf(v);
  H[i] = h;
  L[i] = f2bf(v - bf2f(h));
}

// ---------------- score GEMM v6c: 2-term, eh-only LDS, nt C stores ----------
// Grid 8 x 1563 (q-chunks x ent panels), XCD-swizzled. Block = 128 q-rows x
// 64 ent-rows; wave owns 32 q-rows x 64 ent-cols.
// ent_h panel only in LDS (28,672 B, swizzled) -> 4 blocks/CU (16 waves).
// One barrier. Terms: eh*qh + eh*ql. C stores NON-TEMPORAL via f32x4
// (ext-vector; HIP float4 struct is rejected by the builtin).
__global__ __launch_bounds__(256, 4) void k_score5(
    const ushort_t* __restrict__ Ah, const ushort_t* __restrict__ Al,
    const ushort_t* __restrict__ Bh,
    float* __restrict__ C) {
  constexpr int KP = KP_D;  // 224, 7 K-steps
  __shared__ __align__(16) ushort_t lds[14336];  // 28KB: eh panel only
  const int tid = threadIdx.x;
  const int wave = tid >> 6, lane = tid & 63;
  const int l15 = lane & 15, l4 = lane >> 4;

  int g = (blockIdx.x & 7) * 1563 + (blockIdx.x >> 3);
  const int bm = (g & 7) * 128;       // q chunk (8 of 128)
  const int bn = (g >> 3) * 64;       // ent panel

  // ---- q loads (compiler-scheduled; 16 waves/CU hide the L2 latency) ----
  bf16x8 qh[2][7], ql[2][7];
#pragma unroll
  for (int i = 0; i < 2; ++i) {
    long rowa = (long)(bm + wave * 32 + i * 16 + l15) * KP + l4 * 8;
#pragma unroll
    for (int k = 0; k < 7; ++k) {
      qh[i][k] = *(const bf16x8*)(Ah + rowa + k * 32);
      ql[i][k] = *(const bf16x8*)(Al + rowa + k * 32);
    }
  }

  // ---- stage ent_h panel once (28 chunks x 1KB, swizzled slots) ----
#pragma unroll
  for (int jj = 0; jj < 7; ++jj) {
    int c = wave * 7 + jj;
    int u = c * 64 + lane;              // 16B-unit index, [0,1792)
    int kst = u >> 8;
    int rem = u & 255;
    int r = rem >> 2;
    int slot = rem & 3;
    int srcslot = slot ^ ((r >> 1) & 3);
    int rowg = bn + r; if (rowg > N_ENT - 1) rowg = N_ENT - 1;
    gld16(Bh + (long)rowg * KP + kst * 32 + srcslot * 8, lds + c * 512);
  }
  __syncthreads();

  // ---- compute: mfma(eh, qh) + mfma(eh, ql)  (2 terms) ----
  f32x4 acc[2][4] = {};   // [iq][je]
#pragma unroll
  for (int k = 0; k < 7; ++k) {
    bf16x8 eh[4];
#pragma unroll
    for (int j = 0; j < 4; ++j) {
      int rB = j * 16 + l15;
      int slot = l4 ^ ((rB >> 1) & 3);
      eh[j] = *(const bf16x8*)(lds + k * 2048 + rB * 32 + slot * 8);
    }
#pragma unroll
    for (int i = 0; i < 2; ++i)
#pragma unroll
      for (int j = 0; j < 4; ++j) {
        acc[i][j] = __builtin_amdgcn_mfma_f32_16x16x32_bf16(eh[j], qh[i][k], acc[i][j], 0, 0, 0);
        acc[i][j] = __builtin_amdgcn_mfma_f32_16x16x32_bf16(eh[j], ql[i][k], acc[i][j], 0, 0, 0);
      }
  }

  // ---- store: lane holds 4 consecutive ent columns -> nt f32x4 ----
#pragma unroll
  for (int i = 0; i < 2; ++i) {
    int m = bm + wave * 32 + i * 16 + l15;   // q row = D col = lane&15
#pragma unroll
    for (int j = 0; j < 4; ++j) {
      int nb = bn + j * 16 + l4 * 4;         // ent rows = D rows = l4*4+v
      if (nb < N_ENT) {
        __builtin_nontemporal_store(acc[i][j], (f32x4*)(C + (long)m * N_ENT + nb));
      }
    }
  }
}

// ---------------- MFMA GEMM, f32 A with fused (BN+ReLU+)split (concat/init) ----
template <bool BN_A, bool HAS_BIAS>
__global__ __launch_bounds__(256, 2) void k_mfma_af32(
    const float* __restrict__ A, int lda, int K,
    const ushort_t* __restrict__ Bh, const ushort_t* __restrict__ Bl,
    float* __restrict__ C, int M, int Nc, int Kp, long ldc,
    const float* __restrict__ scale, const float* __restrict__ shift,
    const float* __restrict__ bias) {
  __shared__ __align__(16) ushort_t lds[2 * 16384];
  __shared__ float sc_lds[KP_D], sh_lds[KP_D];
  const int tid = threadIdx.x;
  const int wave = tid >> 6, lane = tid & 63;
  const int bm = blockIdx.x * 128, bn = blockIdx.y * 128;
  const int wr = (wave >> 1) * 64, wc = (wave & 1) * 64;
  const int l15 = lane & 15, l4 = lane >> 4;
  const int NT = Kp >> 5;

  if (BN_A) {
    for (int i = tid; i < Kp; i += 256) {
      sc_lds[i] = (i < K) ? scale[i] : 0.f;
      sh_lds[i] = (i < K) ? shift[i] : 0.f;
    }
    __syncthreads();
  }

  const int ar = tid >> 1;
  const int acb = (tid & 1) * 16;
  int arow = bm + ar; if (arow > M - 1) arow = M - 1;
  const int aswz = (ar >> 1) & 3;
  const int s0 = (((acb >> 3) + 0) ^ aswz) * 8;
  const int s1 = (((acb >> 3) + 1) ^ aswz) * 8;

  auto loadA = [&](int kt, float4* va) {
    int kc = kt * 32 + acb;
    const float* ap = A + (long)arow * lda + kc;
    if (kc + 16 <= K) {
#pragma unroll
      for (int q = 0; q < 4; q++) va[q] = *(const float4*)(ap + q * 4);
    } else {
#pragma unroll
      for (int q = 0; q < 4; q++) {
        float t0 = (kc + q * 4 + 0 < K) ? ap[q * 4 + 0] : 0.f;
        float t1 = (kc + q * 4 + 1 < K) ? ap[q * 4 + 1] : 0.f;
        float t2 = (kc + q * 4 + 2 < K) ? ap[q * 4 + 2] : 0.f;
        float t3 = (kc + q * 4 + 3 < K) ? ap[q * 4 + 3] : 0.f;
        va[q] = make_float4(t0, t1, t2, t3);
      }
    }
  };

  auto writeA = [&](int kt, int ph, float4* va) {
    float v[16];
#pragma unroll
    for (int q = 0; q < 4; q++) {
      v[q * 4 + 0] = va[q].x; v[q * 4 + 1] = va[q].y;
      v[q * 4 + 2] = va[q].z; v[q * 4 + 3] = va[q].w;
    }
    if (BN_A) {
      int kc = kt * 32 + acb;
#pragma unroll
      for (int e = 0; e < 16; e++) {
        int col = kc + e;
        if (col < K) v[e] = fmaxf(fmaf(v[e], sc_lds[col], sh_lds[col]), 0.f);
      }
    }
    unsigned hh[8], ll[8];
#pragma unroll
    for (int e = 0; e < 8; e++) {
      ushort_t h0 = f2bf(v[2 * e]), h1 = f2bf(v[2 * e + 1]);
      ushort_t l0 = f2bf(v[2 * e] - bf2f(h0)), l1 = f2bf(v[2 * e + 1] - bf2f(h1));
      hh[e] = (unsigned)h0 | ((unsigned)h1 << 16);
      ll[e] = (unsigned)l0 | ((unsigned)l1 << 16);
    }
    ushort_t* baseA = lds + ph * 16384 + ar * 32;
    *(uint4*)(baseA + s0) = make_uint4(hh[0], hh[1], hh[2], hh[3]);
    *(uint4*)(baseA + s1) = make_uint4(hh[4], hh[5], hh[6], hh[7]);
    ushort_t* baseL = baseA + 4096;
    *(uint4*)(baseL + s0) = make_uint4(ll[0], ll[1], ll[2], ll[3]);
    *(uint4*)(baseL + s1) = make_uint4(ll[4], ll[5], ll[6], ll[7]);
  };

  auto stageB = [&](int kt, int ph) {
#pragma unroll
    for (int j = 0; j < 4; ++j) {
      int c = 16 + wave * 4 + j;
      int buf = c >> 3;
      int r = (c & 7) * 16 + (lane >> 2);
      int sg = (lane & 3) ^ ((r >> 1) & 3);
      const ushort_t* bp = (buf == 2) ? Bh : Bl;
      int rowg = bn + r; if (rowg > Nc - 1) rowg = Nc - 1;
      gld16(bp + (long)rowg * Kp + kt * 32 + sg * 8, lds + ph * 16384 + c * 512);
    }
  };

  f32x4 acc[4][4] = {};
  {
    float4 va[4];
    loadA(0, va);
    writeA(0, 0, va);
    stageB(0, 0);
  }
  __syncthreads();
  int p = 0;
  for (int t = 0; t < NT; ++t) {
    float4 va[4];
    const bool pre = (t + 1 < NT);
    if (pre) {
      loadA(t + 1, va);
      stageB(t + 1, p ^ 1);
    }
    const ushort_t* base = lds + p * 16384;
    bf16x8 a_h[4], a_l[4], b_h[4], b_l[4];
#pragma unroll
    for (int i = 0; i < 4; i++) {
      int rA = wr + i * 16 + l15;
      int sA = (l4 ^ ((rA >> 1) & 3)) * 8;
      a_h[i] = *(const bf16x8*)(base + rA * 32 + sA);
      a_l[i] = *(const bf16x8*)(base + 4096 + rA * 32 + sA);
      int rB = wc + i * 16 + l15;
      int sB = (l4 ^ ((rB >> 1) & 3)) * 8;
      b_h[i] = *(const bf16x8*)(base + 8192 + rB * 32 + sB);
      b_l[i] = *(const bf16x8*)(base + 12288 + rB * 32 + sB);
    }
#pragma unroll
    for (int i = 0; i < 4; i++)
#pragma unroll
      for (int j = 0; j < 4; j++) {
        acc[i][j] = __builtin_amdgcn_mfma_f32_16x16x32_bf16(a_h[i], b_h[j], acc[i][j], 0, 0, 0);
        acc[i][j] = __builtin_amdgcn_mfma_f32_16x16x32_bf16(a_l[i], b_h[j], acc[i][j], 0, 0, 0);
        acc[i][j] = __builtin_amdgcn_mfma_f32_16x16x32_bf16(a_h[i], b_l[j], acc[i][j], 0, 0, 0);
      }
    if (pre) writeA(t + 1, p ^ 1, va);
    __syncthreads();
    p ^= 1;
  }

#pragma unroll
  for (int i = 0; i < 4; i++) {
    int mrow = bm + wr + i * 16 + l4 * 4;
#pragma unroll
    for (int j = 0; j < 4; j++) {
      int n = bn + wc + j * 16 + l15;
      if (n >= Nc) continue;
      float bb = HAS_BIAS ? bias[n] : 0.f;
#pragma unroll
      for (int v = 0; v < 4; v++) {
        int m = mrow + v;
        if (m < M) C[(long)m * ldc + n] = acc[i][j][v] + bb;
      }
    }
  }
}

// ---------------- small f32 GEMM (tiny rel transforms) ----------------
template <int TM, int TN>
__global__ __launch_bounds__(256) void k_gemm_abt(
    const float* __restrict__ A, const float* __restrict__ Bm, float* __restrict__ C,
    int M, int Nc, int K, long ldc) {
  constexpr int BM = TM * 16, BN = TN * 16, KC = 20;
  __shared__ float As[BM * KC];
  __shared__ float Bs[BN * KC];
  const int tid = threadIdx.x;
  const int tx = tid & 15, ty = tid >> 4;
  const int bm = blockIdx.x * BM, bn = blockIdx.y * BN;
  float acc[TM][TN];
#pragma unroll
  for (int i = 0; i < TM; i++)
#pragma unroll
    for (int j = 0; j < TN; j++) acc[i][j] = 0.f;
  for (int kc = 0; kc < K; kc += KC) {
    for (int i4 = tid; i4 < BM * 5; i4 += 256) {
      int r = i4 / 5, kq = (i4 - r * 5) * 4;
      int row = bm + r; if (row > M - 1) row = M - 1;
      *(float4*)(As + r * KC + kq) = *(const float4*)(A + (long)row * K + kc + kq);
    }
    for (int i4 = tid; i4 < BN * 5; i4 += 256) {
      int r = i4 / 5, kq = (i4 - r * 5) * 4;
      int row = bn + r; if (row > Nc - 1) row = Nc - 1;
      *(float4*)(Bs + r * KC + kq) = *(const float4*)(Bm + (long)row * K + kc + kq);
    }
    __syncthreads();
#pragma unroll
    for (int k4 = 0; k4 < KC; k4 += 4) {
      float4 af[TM], bf[TN];
#pragma unroll
      for (int i = 0; i < TM; i++) af[i] = *(const float4*)(As + (i * 16 + ty) * KC + k4);
#pragma unroll
      for (int j = 0; j < TN; j++) bf[j] = *(const float4*)(Bs + (j * 16 + tx) * KC + k4);
#pragma unroll
      for (int i = 0; i < TM; i++)
#pragma unroll
        for (int j = 0; j < TN; j++) {
          acc[i][j] = fmaf(af[i].x, bf[j].x, acc[i][j]);
          acc[i][j] = fmaf(af[i].y, bf[j].y, acc[i][j]);
          acc[i][j] = fmaf(af[i].z, bf[j].z, acc[i][j]);
          acc[i][j] = fmaf(af[i].w, bf[j].w, acc[i][j]);
        }
    }
    __syncthreads();
  }
#pragma unroll
  for (int i = 0; i < TM; i++) {
    int m = bm + i * 16 + ty;
    if (m >= M) continue;
#pragma unroll
    for (int j = 0; j < TN; j++) {
      int n = bn + j * 16 + tx;
      if (n < Nc) C[(long)m * ldc + n] = acc[i][j];
    }
  }
}

__global__ void k_transpose(const float* __restrict__ s, float* __restrict__ d, int R, int C) {
  int i = blockIdx.x * 256 + threadIdx.x;
  if (i < R * C) { int r = i / C, c = i - r * C; d[c * R + r] = s[i]; }
}

// ---------------------------------------------------------------------------

extern "C" void kernel_launch(void* const* d_in, const int* in_sizes, int n_in,
                              void* d_out, int out_size, void* d_ws, size_t ws_size,
                              hipStream_t stream) {
  const int* src_id = (const int*)d_in[0];
  const int* dst_id = (const int*)d_in[1];
  const int* e_type = (const int*)d_in[2];
  const int* subj = (const int*)d_in[3];
  const int* rel = (const int*)d_in[4];
  const float* emb_h = (const float*)d_in[5];
  const float* emb_e = (const float*)d_in[6];
  const float* lin_w = (const float*)d_in[7];
  const float* lin_b = (const float*)d_in[8];
  const float* rel_wt = (const float*)d_in[9];
  const float* w_rel = (const float*)d_in[10];
  const float* agg_bn_g = (const float*)d_in[11];
  const float* agg_bn_b = (const float*)d_in[12];
  const float* cell_bn_g = (const float*)d_in[13];
  const float* cell_bn_b = (const float*)d_in[14];
  const float* concat_w = (const float*)d_in[15];
  const float* concat_b = (const float*)d_in[16];
  float* out = (float*)d_out;

  // ---- d_ws: only score-GEMM operands (read while d_out is written) ----
  char* w = (char*)d_ws;
  ushort_t* ent_h = (ushort_t*)(w + 0);           // 44,800,000
  ushort_t* ent_l = (ushort_t*)(w + 44800000);    // 44,800,000 (written, unused by score)
  ushort_t* q_h   = (ushort_t*)(w + 89600000);    //    458,752
  ushort_t* q_l   = (ushort_t*)(w + 90112000);    //    458,752

  // ---- d_out front as temp (all dead before score GEMM) ----
  char* ob = (char*)d_out;
  float* ent    = (float*)(ob + 0);             // 80,000,000
  float* tmp    = (float*)(ob + 80000000);      // 80,000,000
  double* part  = (double*)(ob + 160000000);    //  6,553,600
  int* counts   = (int*)(ob + 166600000);       //    400,000
  int* row_ptr  = (int*)(ob + 167000000);
  int* cursor   = (int*)(ob + 167400000);
  int* csr_src  = (int*)(ob + 167800000);       //  1,600,000
  int* csr_et   = (int*)(ob + 169400000);       //  1,600,000
  float* relA   = (float*)(ob + 171800000);     //    380,000
  float* relB   = (float*)(ob + 172180000);     //    380,000
  float* embeT  = (float*)(ob + 172560000);     //     80,000
  float* wrT    = (float*)(ob + 172640000);     //    160,000
  ushort_t* linw_h = (ushort_t*)(ob + 172800000);  // 51,200
  ushort_t* linw_l = (ushort_t*)(ob + 172851200);  // 51,200
  ushort_t* cw0_h  = (ushort_t*)(ob + 172902400);  // 89,600
  ushort_t* cw0_l  = (ushort_t*)(ob + 172992000);
  ushort_t* cw1_h  = (ushort_t*)(ob + 173081600);
  ushort_t* cw1_l  = (ushort_t*)(ob + 173171200);
  float* scaleb = (float*)(ob + 173260800);     // 1,024
  float* shiftb = (float*)(ob + 173261824);     // 1,024
  int* bsum     = (int*)(ob + 173262848);       //   512

  // ---- CSR build (real edges only) ----
  (void)hipMemsetAsync(counts, 0, N_ENT * sizeof(int), stream);
  k_hist<<<(N_EDGE + 255) / 256, 256, 0, stream>>>(dst_id, counts);
  const int NB = (N_ENT + 1023) / 1024;  // 98
  k_scan_block<<<NB, 256, 0, stream>>>(counts, row_ptr, bsum);
  k_scan_tops<<<1, 256, 0, stream>>>(bsum, NB);
  k_scan_add<<<(N_ENT + 255) / 256, 256, 0, stream>>>(row_ptr, bsum, cursor);
  k_fill<<<(N_EDGE + 255) / 256, 256, 0, stream>>>(src_id, dst_id, e_type, cursor,
                                                   csr_src, csr_et);

  // ---- weight prep ----
  k_tsplit<<<(D_ * KP_D0 + 255) / 256, 256, 0, stream>>>(lin_w, D0_, D_, KP_D0,
                                                         linw_h, linw_l);
  k_tsplit<<<(D_ * KP_D + 255) / 256, 256, 0, stream>>>(concat_w, D_, D_, KP_D,
                                                        cw0_h, cw0_l);
  k_tsplit<<<(D_ * KP_D + 255) / 256, 256, 0, stream>>>(concat_w + D_ * D_, D_, D_,
                                                        KP_D, cw1_h, cw1_l);
  k_transpose<<<(D0_ * D_ + 255) / 256, 256, 0, stream>>>(emb_e, embeT, D0_, D_);
  k_transpose<<<(D_ * D_ + 255) / 256, 256, 0, stream>>>(w_rel, wrT, D_, D_);

  const int GM = (N_ENT + 127) / 128;  // 782

  // ---- init projections (A = emb_h f32, fused split in-kernel) ----
  k_mfma_af32<false, true><<<dim3(GM, 2), 256, 0, stream>>>(
      emb_h, D0_, D0_, linw_h, linw_l, ent, N_ENT, D_, KP_D0, (long)D_,
      nullptr, nullptr, lin_b);
  k_gemm_abt<8, 4><<<dim3(4, 4), 256, 0, stream>>>(rel_wt, embeT, relA, NREL_, D_,
                                                   D0_, (long)D_);

  // ================= layer 0 =================
  k_aggregate<false><<<N_ENT, 256, 0, stream>>>(ent, relA, row_ptr, counts,
                                                csr_src, csr_et, tmp, nullptr, nullptr);
  k_colstats<<<GSTAT2, 64, 0, stream>>>(tmp, part);
  k_bn_fin<<<D_, 256, 0, stream>>>(part, agg_bn_g, agg_bn_b, scaleb, shiftb);
  k_mfma_af32<true, true><<<dim3(GM, 2), 256, 0, stream>>>(
      tmp, D_, D_, cw0_h, cw0_l, ent, N_ENT, D_, KP_D, (long)D_,
      scaleb, shiftb, concat_b);
  k_colstats<<<GSTAT2, 64, 0, stream>>>(ent, part);
  k_bn_fin<<<D_, 256, 0, stream>>>(part, cell_bn_g, cell_bn_b, scaleb, shiftb);
  // cell-BN0 not materialized: fused into layer-1 aggregate's gather
  k_gemm_abt<8, 4><<<dim3(4, 4), 256, 0, stream>>>(relA, wrT, relB, NREL_, D_, D_,
                                                   (long)D_);

  // ================= layer 1 =================
  k_aggregate<true><<<N_ENT, 256, 0, stream>>>(ent, relB, row_ptr, counts,
                                               csr_src, csr_et, tmp, scaleb, shiftb);
  k_colstats<<<GSTAT2, 64, 0, stream>>>(tmp, part);
  k_bn_fin<<<D_, 256, 0, stream>>>(part, agg_bn_g + D_, agg_bn_b + D_, scaleb, shiftb);
  k_mfma_af32<true, true><<<dim3(GM, 2), 256, 0, stream>>>(
      tmp, D_, D_, cw1_h, cw1_l, ent, N_ENT, D_, KP_D, (long)D_,
      scaleb, shiftb, concat_b + D_);
  k_colstats<<<GSTAT2, 64, 0, stream>>>(ent, part);
  k_bn_fin<<<D_, 256, 0, stream>>>(part, cell_bn_g + D_, cell_bn_b + D_, scaleb, shiftb);
  k_norm_split<<<2048, 256, 0, stream>>>(ent, scaleb, shiftb, ent_h, ent_l);
  k_gemm_abt<8, 4><<<dim3(4, 4), 256, 0, stream>>>(relB, wrT, relA, NREL_, D_, D_,
                                                   (long)D_);

  // ---- score operands ----
  k_qsplit<<<(B_ * KP_D + 255) / 256, 256, 0, stream>>>(ent, relA, subj, rel,
                                                        q_h, q_l);

  // ---- DistMult score: 2-term, eh-only LDS, nt stores, 4 blocks/CU ----
  k_score5<<<dim3(8 * 1563), 256, 0, stream>>>(q_h, q_l, ent_h, out);
}

// Round 15
// 1026.521 us; speedup vs baseline: 1.1081x; 1.1038x over previous
//
#include <hip/hip_runtime.h>

// ---------------------------------------------------------------------------
// CompGCN-style network. MFMA split-bf16 (hi/lo, 3-term) GEMMs.
// Round 15:
//   - score GEMM reverted to r10's k_score4 (best measured: 260us, 3-term,
//     57KB LDS, 2 blocks/CU, temporal float4 stores). nt-store and 4-blk/CU
//     variants refuted by counters (L2 dirty-footprint churn / partial-sector
//     write amplification).
//   - k_aggregate rewritten: one WAVE per node, lane<50 x float4 (4 nodes per
//     256-block). 4x fewer load/FMA instructions, cs/ct loaded 50x not 200x.
//   N=100000 ents, E=400000 edges, D=200, D0=100, NREL=475, B=1024, L=2
// ---------------------------------------------------------------------------

#define N_ENT  100000
#define N_EDGE 400000
#define D_     200
#define D0_    100
#define NREL_  475
#define B_     1024
#define GSTAT2 2048
#define KP_D   224   // D padded to multiple of 32
#define KP_D0  128   // D0 padded

typedef unsigned short ushort_t;
typedef __attribute__((ext_vector_type(8))) short bf16x8;
typedef __attribute__((ext_vector_type(4))) float f32x4;

__device__ __forceinline__ ushort_t f2bf(float x) {
  unsigned u = __float_as_uint(x);
  return (ushort_t)((u + 0x7FFFu + ((u >> 16) & 1u)) >> 16);
}
__device__ __forceinline__ float bf2f(ushort_t h) {
  return __uint_as_float(((unsigned)h) << 16);
}

__device__ __forceinline__ void gld16(const void* g, void* l) {
  __builtin_amdgcn_global_load_lds(
      (const __attribute__((address_space(1))) unsigned*)g,
      (__attribute__((address_space(3))) unsigned*)l, 16, 0, 0);
}

// ---------------- CSR build (real edges only; self-loops streamed) ----------

__global__ void k_hist(const int* __restrict__ dst_id, int* __restrict__ cnt) {
  int e = blockIdx.x * 256 + threadIdx.x;
  if (e < N_EDGE) atomicAdd(&cnt[dst_id[e]], 1);
}

__global__ __launch_bounds__(256) void k_scan_block(const int* __restrict__ cnt,
                                                    int* __restrict__ rp,
                                                    int* __restrict__ bsum) {
  __shared__ int sm[256];
  int tid = threadIdx.x;
  int base = blockIdx.x * 1024 + tid * 4;
  int v0 = (base + 0 < N_ENT) ? cnt[base + 0] : 0;
  int v1 = (base + 1 < N_ENT) ? cnt[base + 1] : 0;
  int v2 = (base + 2 < N_ENT) ? cnt[base + 2] : 0;
  int v3 = (base + 3 < N_ENT) ? cnt[base + 3] : 0;
  int tsum = v0 + v1 + v2 + v3;
  sm[tid] = tsum;
  __syncthreads();
  for (int off = 1; off < 256; off <<= 1) {
    int t = (tid >= off) ? sm[tid - off] : 0;
    __syncthreads();
    sm[tid] += t;
    __syncthreads();
  }
  int run = sm[tid] - tsum;
  if (base + 0 < N_ENT) { rp[base + 0] = run; } run += v0;
  if (base + 1 < N_ENT) { rp[base + 1] = run; } run += v1;
  if (base + 2 < N_ENT) { rp[base + 2] = run; } run += v2;
  if (base + 3 < N_ENT) { rp[base + 3] = run; }
  if (tid == 255) bsum[blockIdx.x] = sm[255];
}

__global__ void k_scan_tops(int* __restrict__ bsum, int nb) {
  __shared__ int sm[256];
  int tid = threadIdx.x;
  int v = (tid < nb) ? bsum[tid] : 0;
  sm[tid] = v;
  __syncthreads();
  for (int off = 1; off < 256; off <<= 1) {
    int t = (tid >= off) ? sm[tid - off] : 0;
    __syncthreads();
    sm[tid] += t;
    __syncthreads();
  }
  if (tid < nb) bsum[tid] = sm[tid] - v;
}

__global__ void k_scan_add(int* __restrict__ rp, const int* __restrict__ bsum,
                           int* __restrict__ cursor) {
  int i = blockIdx.x * 256 + threadIdx.x;
  if (i < N_ENT) {
    int r = rp[i] + bsum[i >> 10];
    rp[i] = r;
    cursor[i] = r;
  }
}

__global__ void k_fill(const int* __restrict__ src_id, const int* __restrict__ dst_id,
                       const int* __restrict__ e_type, int* __restrict__ cursor,
                       int* __restrict__ cs, int* __restrict__ ct) {
  int e = blockIdx.x * 256 + threadIdx.x;
  if (e < N_EDGE) {
    int pos = atomicAdd(&cursor[dst_id[e]], 1);
    cs[pos] = src_id[e];
    ct[pos] = e_type[e];
  }
}

// ---------------- aggregation / BN ----------------

// One WAVE per node: lanes 0..49 cover 200 features as float4.
// 4 nodes per 256-thread block. BN: relu(v*scale+shift) fused on gathered rows.
template <bool BN>
__global__ __launch_bounds__(256) void k_aggregate(const float* __restrict__ ent,
                                                   const float* __restrict__ relE,
                                                   const int* __restrict__ rp,
                                                   const int* __restrict__ cnt,
                                                   const int* __restrict__ cs,
                                                   const int* __restrict__ ct,
                                                   float* __restrict__ out,
                                                   const float* __restrict__ scale,
                                                   const float* __restrict__ shift) {
  const int wv = threadIdx.x >> 6;
  const int lane = threadIdx.x & 63;
  const int n = blockIdx.x * 4 + wv;
  if (n >= N_ENT || lane >= 50) return;
  const int f4 = lane * 4;

  float sc[4] = {0, 0, 0, 0}, sh[4] = {0, 0, 0, 0};
  if (BN) {
    float4 s4 = *(const float4*)(scale + f4);
    float4 h4 = *(const float4*)(shift + f4);
    sc[0] = s4.x; sc[1] = s4.y; sc[2] = s4.z; sc[3] = s4.w;
    sh[0] = h4.x; sh[1] = h4.y; sh[2] = h4.z; sh[3] = h4.w;
  }

  // self-loop term (streamed, no gather)
  float ax[4], ay[4] = {0, 0, 0, 0};
  {
    float4 e = *(const float4*)(ent + (long)n * D_ + f4);
    float4 r = *(const float4*)(relE + (long)(NREL_ - 1) * D_ + f4);
    float ee[4] = {e.x, e.y, e.z, e.w};
    float rr[4] = {r.x, r.y, r.z, r.w};
#pragma unroll
    for (int u = 0; u < 4; ++u) {
      if (BN) ee[u] = fmaxf(fmaf(ee[u], sc[u], sh[u]), 0.f);
      ax[u] = ee[u] * rr[u];
    }
  }

  int s0 = rp[n], e0 = s0 + cnt[n];
  int idx = s0;
  for (; idx + 2 <= e0; idx += 2) {
    int sA = cs[idx], tA = ct[idx];
    int sB = cs[idx + 1], tB = ct[idx + 1];
    float4 eA = *(const float4*)(ent + (long)sA * D_ + f4);
    float4 rA = *(const float4*)(relE + (long)tA * D_ + f4);
    float4 eB = *(const float4*)(ent + (long)sB * D_ + f4);
    float4 rB = *(const float4*)(relE + (long)tB * D_ + f4);
    float ea[4] = {eA.x, eA.y, eA.z, eA.w}, ra[4] = {rA.x, rA.y, rA.z, rA.w};
    float eb[4] = {eB.x, eB.y, eB.z, eB.w}, rb[4] = {rB.x, rB.y, rB.z, rB.w};
#pragma unroll
    for (int u = 0; u < 4; ++u) {
      if (BN) {
        ea[u] = fmaxf(fmaf(ea[u], sc[u], sh[u]), 0.f);
        eb[u] = fmaxf(fmaf(eb[u], sc[u], sh[u]), 0.f);
      }
      ax[u] = fmaf(ea[u], ra[u], ax[u]);
      ay[u] = fmaf(eb[u], rb[u], ay[u]);
    }
  }
  if (idx < e0) {
    int sA = cs[idx], tA = ct[idx];
    float4 eA = *(const float4*)(ent + (long)sA * D_ + f4);
    float4 rA = *(const float4*)(relE + (long)tA * D_ + f4);
    float ea[4] = {eA.x, eA.y, eA.z, eA.w}, ra[4] = {rA.x, rA.y, rA.z, rA.w};
#pragma unroll
    for (int u = 0; u < 4; ++u) {
      if (BN) ea[u] = fmaxf(fmaf(ea[u], sc[u], sh[u]), 0.f);
      ax[u] = fmaf(ea[u], ra[u], ax[u]);
    }
  }
  float4 o = make_float4(ax[0] + ay[0], ax[1] + ay[1], ax[2] + ay[2], ax[3] + ay[3]);
  *(float4*)(out + (long)n * D_ + f4) = o;
}

__global__ __launch_bounds__(64) void k_colstats(const float* __restrict__ X,
                                                 double* __restrict__ part) {
  int t = threadIdx.x;
  if (t >= 50) return;
  double s0 = 0, s1 = 0, s2 = 0, s3 = 0, q0 = 0, q1 = 0, q2 = 0, q3 = 0;
  for (int r = blockIdx.x; r < N_ENT; r += GSTAT2) {
    float4 v = *(const float4*)(X + (long)r * D_ + t * 4);
    s0 += v.x; q0 += (double)v.x * v.x;
    s1 += v.y; q1 += (double)v.y * v.y;
    s2 += v.z; q2 += (double)v.z * v.z;
    s3 += v.w; q3 += (double)v.w * v.w;
  }
  long o = (long)blockIdx.x * 400 + t * 4;
  part[o + 0] = s0; part[o + 1] = s1; part[o + 2] = s2; part[o + 3] = s3;
  part[o + 200] = q0; part[o + 201] = q1; part[o + 202] = q2; part[o + 203] = q3;
}

__global__ __launch_bounds__(256) void k_bn_fin(const double* __restrict__ part,
                                                const float* __restrict__ g,
                                                const float* __restrict__ b,
                                                float* __restrict__ scale,
                                                float* __restrict__ shift) {
  int f = blockIdx.x;  // 0..199
  int tid = threadIdx.x;
  double S = 0.0, S2 = 0.0;
  for (int i = tid; i < GSTAT2; i += 256) {
    S += part[(long)i * 400 + f];
    S2 += part[(long)i * 400 + 200 + f];
  }
  __shared__ double smS[256], smS2[256];
  smS[tid] = S; smS2[tid] = S2;
  __syncthreads();
  for (int off = 128; off > 0; off >>= 1) {
    if (tid < off) { smS[tid] += smS[tid + off]; smS2[tid] += smS2[tid + off]; }
    __syncthreads();
  }
  if (tid == 0) {
    double mean = smS[0] / N_ENT;
    double var = smS2[0] / N_ENT - mean * mean;
    double inv = 1.0 / sqrt(var + 1e-5);
    float sc = g[f] * (float)inv;
    scale[f] = sc;
    shift[f] = b[f] - (float)mean * sc;
  }
}

// BN+ReLU in place AND emit bf16 hi/lo padded split (for score-GEMM B side)
__global__ void k_norm_split(float* __restrict__ X, const float* __restrict__ scale,
                             const float* __restrict__ shift,
                             ushort_t* __restrict__ H, ushort_t* __restrict__ L) {
  const long total = (long)N_ENT * (KP_D / 4);
  for (long i4 = (long)blockIdx.x * 256 + threadIdx.x; i4 < total;
       i4 += (long)gridDim.x * 256) {
    int r = (int)(i4 / (KP_D / 4));
    int c4 = (int)(i4 % (KP_D / 4)) * 4;
    float vv[4] = {0.f, 0.f, 0.f, 0.f};
    if (c4 < D_) {
      float4 v = *(float4*)(X + (long)r * D_ + c4);
      vv[0] = fmaxf(fmaf(v.x, scale[c4 + 0], shift[c4 + 0]), 0.f);
      vv[1] = fmaxf(fmaf(v.y, scale[c4 + 1], shift[c4 + 1]), 0.f);
      vv[2] = fmaxf(fmaf(v.z, scale[c4 + 2], shift[c4 + 2]), 0.f);
      vv[3] = fmaxf(fmaf(v.w, scale[c4 + 3], shift[c4 + 3]), 0.f);
      *(float4*)(X + (long)r * D_ + c4) = make_float4(vv[0], vv[1], vv[2], vv[3]);
    }
    ushort_t h[4], l[4];
#pragma unroll
    for (int t = 0; t < 4; t++) {
      h[t] = f2bf(vv[t]);
      l[t] = f2bf(vv[t] - bf2f(h[t]));
    }
    long o = (long)r * KP_D + c4;
    *(uint2*)(H + o) = make_uint2((unsigned)h[0] | ((unsigned)h[1] << 16),
                                  (unsigned)h[2] | ((unsigned)h[3] << 16));
    *(uint2*)(L + o) = make_uint2((unsigned)l[0] | ((unsigned)l[1] << 16),
                                  (unsigned)l[2] | ((unsigned)l[3] << 16));
  }
}

// W [K][Nc] row-major -> transposed split H/L [Nc][Kp]
__global__ void k_tsplit(const float* __restrict__ W, int K, int Nc, int Kp,
                         ushort_t* __restrict__ H, ushort_t* __restrict__ L) {
  int i = blockIdx.x * 256 + threadIdx.x;
  if (i >= Nc * Kp) return;
  int n = i / Kp, kp = i - n * Kp;
  float v = (kp < K) ? W[(long)kp * Nc + n] : 0.f;
  ushort_t h = f2bf(v);
  H[i] = h;
  L[i] = f2bf(v - bf2f(h));
}

// q[b][kp] = ent[subj[b]][kp] * rel_embed[rel[b]][kp], split hi/lo, padded
__global__ void k_qsplit(const float* __restrict__ ent, const float* __restrict__ relE,
                         const int* __restrict__ subj, const int* __restrict__ rel,
                         ushort_t* __restrict__ H, ushort_t* __restrict__ L) {
  int i = blockIdx.x * 256 + threadIdx.x;
  if (i >= B_ * KP_D) return;
  int b = i / KP_D, kp = i - b * KP_D;
  float v = 0.f;
  if (kp < D_)
    v = ent[(long)subj[b] * D_ + kp] * relE[(long)rel[b] * D_ + kp];
  ushort_t h = f2bf(v);
  H[i] = h;
  L[i] = f2bf(v - bf2f(h));
}

// ---------------- score GEMM (r10 config): pinned-layout, swapped MFMA ------
// Grid 8 x 1563 (q-chunks x ent panels), XCD-swizzled. Block = 128 q-rows x
// 64 ent-rows; wave owns 32 q-rows. ent panel (h+l, K=224, XOR-swizzled,
// 57,344 B) staged once; ONE barrier; 3-term mfma(ent, q); temporal float4
// stores (L2 merges 64B row-segments into full lines at 2 blocks/CU).
__global__ __launch_bounds__(256, 2) void k_score4(
    const ushort_t* __restrict__ Ah, const ushort_t* __restrict__ Al,
    const ushort_t* __restrict__ Bh, const ushort_t* __restrict__ Bl,
    float* __restrict__ C) {
  constexpr int KP = KP_D;  // 224, 7 K-steps
  __shared__ __align__(16) ushort_t lds[2 * 14336];
  const int tid = threadIdx.x;
  const int wave = tid >> 6, lane = tid & 63;
  const int l15 = lane & 15, l4 = lane >> 4;

  int g = (blockIdx.x & 7) * 1563 + (blockIdx.x >> 3);
  const int bm = (g & 7) * 128;       // q chunk (8 of 128)
  const int bn = (g >> 3) * 64;       // ent panel

  // ---- q loads: wave's 32 rows, full K, hi+lo (28 x bf16x8) ----
  bf16x8 qh[2][7], ql[2][7];
#pragma unroll
  for (int i = 0; i < 2; ++i) {
    long rowa = (long)(bm + wave * 32 + i * 16 + l15) * KP + l4 * 8;
#pragma unroll
    for (int k = 0; k < 7; ++k) {
      qh[i][k] = *(const bf16x8*)(Ah + rowa + k * 32);
      ql[i][k] = *(const bf16x8*)(Al + rowa + k * 32);
    }
  }

  // ---- stage ent panel once (56 chunks x 1KB, swizzled slots) ----
#pragma unroll
  for (int jj = 0; jj < 14; ++jj) {
    int c = wave * 14 + jj;
    int u = c * 64 + lane;              // 16B-unit index
    int isl = (u >= 1792) ? 1 : 0;      // first 1792 units = h panel
    int u2 = u - isl * 1792;
    int kst = u2 >> 8;
    int rem = u2 & 255;
    int r = rem >> 2;
    int slot = rem & 3;
    int srcslot = slot ^ ((r >> 1) & 3);
    int rowg = bn + r; if (rowg > N_ENT - 1) rowg = N_ENT - 1;
    const ushort_t* src = (isl ? Bl : Bh) + (long)rowg * KP + kst * 32 + srcslot * 8;
    gld16(src, lds + c * 512);
  }
  __syncthreads();

  // ---- compute: mfma(ent_frag, q_frag) -> D[row=ent, col=q], 3 terms ----
  f32x4 acc[2][4] = {};   // [iq][je]
#pragma unroll
  for (int k = 0; k < 7; ++k) {
    bf16x8 eh[4], el[4];
#pragma unroll
    for (int j = 0; j < 4; ++j) {
      int rB = j * 16 + l15;
      int slot = l4 ^ ((rB >> 1) & 3);
      int ad = k * 2048 + rB * 32 + slot * 8;
      eh[j] = *(const bf16x8*)(lds + ad);
      el[j] = *(const bf16x8*)(lds + 14336 + ad);
    }
#pragma unroll
    for (int i = 0; i < 2; ++i)
#pragma unroll
      for (int j = 0; j < 4; ++j) {
        acc[i][j] = __builtin_amdgcn_mfma_f32_16x16x32_bf16(eh[j], qh[i][k], acc[i][j], 0, 0, 0);
        acc[i][j] = __builtin_amdgcn_mfma_f32_16x16x32_bf16(eh[j], ql[i][k], acc[i][j], 0, 0, 0);
        acc[i][j] = __builtin_amdgcn_mfma_f32_16x16x32_bf16(el[j], qh[i][k], acc[i][j], 0, 0, 0);
      }
  }

  // ---- store: lane holds 4 consecutive ent columns -> float4 ----
#pragma unroll
  for (int i = 0; i < 2; ++i) {
    int m = bm + wave * 32 + i * 16 + l15;   // q row = D col = lane&15
#pragma unroll
    for (int j = 0; j < 4; ++j) {
      int nb = bn + j * 16 + l4 * 4;         // ent rows = D rows = l4*4+v
      if (nb < N_ENT) {
        float4 o = make_float4(acc[i][j][0], acc[i][j][1], acc[i][j][2], acc[i][j][3]);
        *(float4*)(C + (long)m * N_ENT + nb) = o;
      }
    }
  }
}

// ---------------- MFMA GEMM, f32 A with fused (BN+ReLU+)split (concat/init) ----
template <bool BN_A, bool HAS_BIAS>
__global__ __launch_bounds__(256, 2) void k_mfma_af32(
    const float* __restrict__ A, int lda, int K,
    const ushort_t* __restrict__ Bh, const ushort_t* __restrict__ Bl,
    float* __restrict__ C, int M, int Nc, int Kp, long ldc,
    const float* __restrict__ scale, const float* __restrict__ shift,
    const float* __restrict__ bias) {
  __shared__ __align__(16) ushort_t lds[2 * 16384];
  __shared__ float sc_lds[KP_D], sh_lds[KP_D];
  const int tid = threadIdx.x;
  const int wave = tid >> 6, lane = tid & 63;
  const int bm = blockIdx.x * 128, bn = blockIdx.y * 128;
  const int wr = (wave >> 1) * 64, wc = (wave & 1) * 64;
  const int l15 = lane & 15, l4 = lane >> 4;
  const int NT = Kp >> 5;

  if (BN_A) {
    for (int i = tid; i < Kp; i += 256) {
      sc_lds[i] = (i < K) ? scale[i] : 0.f;
      sh_lds[i] = (i < K) ? shift[i] : 0.f;
    }
    __syncthreads();
  }

  const int ar = tid >> 1;
  const int acb = (tid & 1) * 16;
  int arow = bm + ar; if (arow > M - 1) arow = M - 1;
  const int aswz = (ar >> 1) & 3;
  const int s0 = (((acb >> 3) + 0) ^ aswz) * 8;
  const int s1 = (((acb >> 3) + 1) ^ aswz) * 8;

  auto loadA = [&](int kt, float4* va) {
    int kc = kt * 32 + acb;
    const float* ap = A + (long)arow * lda + kc;
    if (kc + 16 <= K) {
#pragma unroll
      for (int q = 0; q < 4; q++) va[q] = *(const float4*)(ap + q * 4);
    } else {
#pragma unroll
      for (int q = 0; q < 4; q++) {
        float t0 = (kc + q * 4 + 0 < K) ? ap[q * 4 + 0] : 0.f;
        float t1 = (kc + q * 4 + 1 < K) ? ap[q * 4 + 1] : 0.f;
        float t2 = (kc + q * 4 + 2 < K) ? ap[q * 4 + 2] : 0.f;
        float t3 = (kc + q * 4 + 3 < K) ? ap[q * 4 + 3] : 0.f;
        va[q] = make_float4(t0, t1, t2, t3);
      }
    }
  };

  auto writeA = [&](int kt, int ph, float4* va) {
    float v[16];
#pragma unroll
    for (int q = 0; q < 4; q++) {
      v[q * 4 + 0] = va[q].x; v[q * 4 + 1] = va[q].y;
      v[q * 4 + 2] = va[q].z; v[q * 4 + 3] = va[q].w;
    }
    if (BN_A) {
      int kc = kt * 32 + acb;
#pragma unroll
      for (int e = 0; e < 16; e++) {
        int col = kc + e;
        if (col < K) v[e] = fmaxf(fmaf(v[e], sc_lds[col], sh_lds[col]), 0.f);
      }
    }
    unsigned hh[8], ll[8];
#pragma unroll
    for (int e = 0; e < 8; e++) {
      ushort_t h0 = f2bf(v[2 * e]), h1 = f2bf(v[2 * e + 1]);
      ushort_t l0 = f2bf(v[2 * e] - bf2f(h0)), l1 = f2bf(v[2 * e + 1] - bf2f(h1));
      hh[e] = (unsigned)h0 | ((unsigned)h1 << 16);
      ll[e] = (unsigned)l0 | ((unsigned)l1 << 16);
    }
    ushort_t* baseA = lds + ph * 16384 + ar * 32;
    *(uint4*)(baseA + s0) = make_uint4(hh[0], hh[1], hh[2], hh[3]);
    *(uint4*)(baseA + s1) = make_uint4(hh[4], hh[5], hh[6], hh[7]);
    ushort_t* baseL = baseA + 4096;
    *(uint4*)(baseL + s0) = make_uint4(ll[0], ll[1], ll[2], ll[3]);
    *(uint4*)(baseL + s1) = make_uint4(ll[4], ll[5], ll[6], ll[7]);
  };

  auto stageB = [&](int kt, int ph) {
#pragma unroll
    for (int j = 0; j < 4; ++j) {
      int c = 16 + wave * 4 + j;
      int buf = c >> 3;
      int r = (c & 7) * 16 + (lane >> 2);
      int sg = (lane & 3) ^ ((r >> 1) & 3);
      const ushort_t* bp = (buf == 2) ? Bh : Bl;
      int rowg = bn + r; if (rowg > Nc - 1) rowg = Nc - 1;
      gld16(bp + (long)rowg * Kp + kt * 32 + sg * 8, lds + ph * 16384 + c * 512);
    }
  };

  f32x4 acc[4][4] = {};
  {
    float4 va[4];
    loadA(0, va);
    writeA(0, 0, va);
    stageB(0, 0);
  }
  __syncthreads();
  int p = 0;
  for (int t = 0; t < NT; ++t) {
    float4 va[4];
    const bool pre = (t + 1 < NT);
    if (pre) {
      loadA(t + 1, va);
      stageB(t + 1, p ^ 1);
    }
    const ushort_t* base = lds + p * 16384;
    bf16x8 a_h[4], a_l[4], b_h[4], b_l[4];
#pragma unroll
    for (int i = 0; i < 4; i++) {
      int rA = wr + i * 16 + l15;
      int sA = (l4 ^ ((rA >> 1) & 3)) * 8;
      a_h[i] = *(const bf16x8*)(base + rA * 32 + sA);
      a_l[i] = *(const bf16x8*)(base + 4096 + rA * 32 + sA);
      int rB = wc + i * 16 + l15;
      int sB = (l4 ^ ((rB >> 1) & 3)) * 8;
      b_h[i] = *(const bf16x8*)(base + 8192 + rB * 32 + sB);
      b_l[i] = *(const bf16x8*)(base + 12288 + rB * 32 + sB);
    }
#pragma unroll
    for (int i = 0; i < 4; i++)
#pragma unroll
      for (int j = 0; j < 4; j++) {
        acc[i][j] = __builtin_amdgcn_mfma_f32_16x16x32_bf16(a_h[i], b_h[j], acc[i][j], 0, 0, 0);
        acc[i][j] = __builtin_amdgcn_mfma_f32_16x16x32_bf16(a_l[i], b_h[j], acc[i][j], 0, 0, 0);
        acc[i][j] = __builtin_amdgcn_mfma_f32_16x16x32_bf16(a_h[i], b_l[j], acc[i][j], 0, 0, 0);
      }
    if (pre) writeA(t + 1, p ^ 1, va);
    __syncthreads();
    p ^= 1;
  }

#pragma unroll
  for (int i = 0; i < 4; i++) {
    int mrow = bm + wr + i * 16 + l4 * 4;
#pragma unroll
    for (int j = 0; j < 4; j++) {
      int n = bn + wc + j * 16 + l15;
      if (n >= Nc) continue;
      float bb = HAS_BIAS ? bias[n] : 0.f;
#pragma unroll
      for (int v = 0; v < 4; v++) {
        int m = mrow + v;
        if (m < M) C[(long)m * ldc + n] = acc[i][j][v] + bb;
      }
    }
  }
}

// ---------------- small f32 GEMM (tiny rel transforms) ----------------
template <int TM, int TN>
__global__ __launch_bounds__(256) void k_gemm_abt(
    const float* __restrict__ A, const float* __restrict__ Bm, float* __restrict__ C,
    int M, int Nc, int K, long ldc) {
  constexpr int BM = TM * 16, BN = TN * 16, KC = 20;
  __shared__ float As[BM * KC];
  __shared__ float Bs[BN * KC];
  const int tid = threadIdx.x;
  const int tx = tid & 15, ty = tid >> 4;
  const int bm = blockIdx.x * BM, bn = blockIdx.y * BN;
  float acc[TM][TN];
#pragma unroll
  for (int i = 0; i < TM; i++)
#pragma unroll
    for (int j = 0; j < TN; j++) acc[i][j] = 0.f;
  for (int kc = 0; kc < K; kc += KC) {
    for (int i4 = tid; i4 < BM * 5; i4 += 256) {
      int r = i4 / 5, kq = (i4 - r * 5) * 4;
      int row = bm + r; if (row > M - 1) row = M - 1;
      *(float4*)(As + r * KC + kq) = *(const float4*)(A + (long)row * K + kc + kq);
    }
    for (int i4 = tid; i4 < BN * 5; i4 += 256) {
      int r = i4 / 5, kq = (i4 - r * 5) * 4;
      int row = bn + r; if (row > Nc - 1) row = Nc - 1;
      *(float4*)(Bs + r * KC + kq) = *(const float4*)(Bm + (long)row * K + kc + kq);
    }
    __syncthreads();
#pragma unroll
    for (int k4 = 0; k4 < KC; k4 += 4) {
      float4 af[TM], bf[TN];
#pragma unroll
      for (int i = 0; i < TM; i++) af[i] = *(const float4*)(As + (i * 16 + ty) * KC + k4);
#pragma unroll
      for (int j = 0; j < TN; j++) bf[j] = *(const float4*)(Bs + (j * 16 + tx) * KC + k4);
#pragma unroll
      for (int i = 0; i < TM; i++)
#pragma unroll
        for (int j = 0; j < TN; j++) {
          acc[i][j] = fmaf(af[i].x, bf[j].x, acc[i][j]);
          acc[i][j] = fmaf(af[i].y, bf[j].y, acc[i][j]);
          acc[i][j] = fmaf(af[i].z, bf[j].z, acc[i][j]);
          acc[i][j] = fmaf(af[i].w, bf[j].w, acc[i][j]);
        }
    }
    __syncthreads();
  }
#pragma unroll
  for (int i = 0; i < TM; i++) {
    int m = bm + i * 16 + ty;
    if (m >= M) continue;
#pragma unroll
    for (int j = 0; j < TN; j++) {
      int n = bn + j * 16 + tx;
      if (n < Nc) C[(long)m * ldc + n] = acc[i][j];
    }
  }
}

__global__ void k_transpose(const float* __restrict__ s, float* __restrict__ d, int R, int C) {
  int i = blockIdx.x * 256 + threadIdx.x;
  if (i < R * C) { int r = i / C, c = i - r * C; d[c * R + r] = s[i]; }
}

// ---------------------------------------------------------------------------

extern "C" void kernel_launch(void* const* d_in, const int* in_sizes, int n_in,
                              void* d_out, int out_size, void* d_ws, size_t ws_size,
                              hipStream_t stream) {
  const int* src_id = (const int*)d_in[0];
  const int* dst_id = (const int*)d_in[1];
  const int* e_type = (const int*)d_in[2];
  const int* subj = (const int*)d_in[3];
  const int* rel = (const int*)d_in[4];
  const float* emb_h = (const float*)d_in[5];
  const float* emb_e = (const float*)d_in[6];
  const float* lin_w = (const float*)d_in[7];
  const float* lin_b = (const float*)d_in[8];
  const float* rel_wt = (const float*)d_in[9];
  const float* w_rel = (const float*)d_in[10];
  const float* agg_bn_g = (const float*)d_in[11];
  const float* agg_bn_b = (const float*)d_in[12];
  const float* cell_bn_g = (const float*)d_in[13];
  const float* cell_bn_b = (const float*)d_in[14];
  const float* concat_w = (const float*)d_in[15];
  const float* concat_b = (const float*)d_in[16];
  float* out = (float*)d_out;

  // ---- d_ws: only score-GEMM operands (read while d_out is written) ----
  char* w = (char*)d_ws;
  ushort_t* ent_h = (ushort_t*)(w + 0);           // 44,800,000
  ushort_t* ent_l = (ushort_t*)(w + 44800000);    // 44,800,000
  ushort_t* q_h   = (ushort_t*)(w + 89600000);    //    458,752
  ushort_t* q_l   = (ushort_t*)(w + 90112000);    //    458,752

  // ---- d_out front as temp (all dead before score GEMM) ----
  char* ob = (char*)d_out;
  float* ent    = (float*)(ob + 0);             // 80,000,000
  float* tmp    = (float*)(ob + 80000000);      // 80,000,000
  double* part  = (double*)(ob + 160000000);    //  6,553,600
  int* counts   = (int*)(ob + 166600000);       //    400,000
  int* row_ptr  = (int*)(ob + 167000000);
  int* cursor   = (int*)(ob + 167400000);
  int* csr_src  = (int*)(ob + 167800000);       //  1,600,000
  int* csr_et   = (int*)(ob + 169400000);       //  1,600,000
  float* relA   = (float*)(ob + 171800000);     //    380,000
  float* relB   = (float*)(ob + 172180000);     //    380,000
  float* embeT  = (float*)(ob + 172560000);     //     80,000
  float* wrT    = (float*)(ob + 172640000);     //    160,000
  ushort_t* linw_h = (ushort_t*)(ob + 172800000);  // 51,200
  ushort_t* linw_l = (ushort_t*)(ob + 172851200);  // 51,200
  ushort_t* cw0_h  = (ushort_t*)(ob + 172902400);  // 89,600
  ushort_t* cw0_l  = (ushort_t*)(ob + 172992000);
  ushort_t* cw1_h  = (ushort_t*)(ob + 173081600);
  ushort_t* cw1_l  = (ushort_t*)(ob + 173171200);
  float* scaleb = (float*)(ob + 173260800);     // 1,024
  float* shiftb = (float*)(ob + 173261824);     // 1,024
  int* bsum     = (int*)(ob + 173262848);       //   512

  // ---- CSR build (real edges only) ----
  (void)hipMemsetAsync(counts, 0, N_ENT * sizeof(int), stream);
  k_hist<<<(N_EDGE + 255) / 256, 256, 0, stream>>>(dst_id, counts);
  const int NB = (N_ENT + 1023) / 1024;  // 98
  k_scan_block<<<NB, 256, 0, stream>>>(counts, row_ptr, bsum);
  k_scan_tops<<<1, 256, 0, stream>>>(bsum, NB);
  k_scan_add<<<(N_ENT + 255) / 256, 256, 0, stream>>>(row_ptr, bsum, cursor);
  k_fill<<<(N_EDGE + 255) / 256, 256, 0, stream>>>(src_id, dst_id, e_type, cursor,
                                                   csr_src, csr_et);

  // ---- weight prep ----
  k_tsplit<<<(D_ * KP_D0 + 255) / 256, 256, 0, stream>>>(lin_w, D0_, D_, KP_D0,
                                                         linw_h, linw_l);
  k_tsplit<<<(D_ * KP_D + 255) / 256, 256, 0, stream>>>(concat_w, D_, D_, KP_D,
                                                        cw0_h, cw0_l);
  k_tsplit<<<(D_ * KP_D + 255) / 256, 256, 0, stream>>>(concat_w + D_ * D_, D_, D_,
                                                        KP_D, cw1_h, cw1_l);
  k_transpose<<<(D0_ * D_ + 255) / 256, 256, 0, stream>>>(emb_e, embeT, D0_, D_);
  k_transpose<<<(D_ * D_ + 255) / 256, 256, 0, stream>>>(w_rel, wrT, D_, D_);

  const int GM = (N_ENT + 127) / 128;  // 782
  const int GA = (N_ENT + 3) / 4;      // 25000 aggregate blocks

  // ---- init projections (A = emb_h f32, fused split in-kernel) ----
  k_mfma_af32<false, true><<<dim3(GM, 2), 256, 0, stream>>>(
      emb_h, D0_, D0_, linw_h, linw_l, ent, N_ENT, D_, KP_D0, (long)D_,
      nullptr, nullptr, lin_b);
  k_gemm_abt<8, 4><<<dim3(4, 4), 256, 0, stream>>>(rel_wt, embeT, relA, NREL_, D_,
                                                   D0_, (long)D_);

  // ================= layer 0 =================
  k_aggregate<false><<<GA, 256, 0, stream>>>(ent, relA, row_ptr, counts,
                                             csr_src, csr_et, tmp, nullptr, nullptr);
  k_colstats<<<GSTAT2, 64, 0, stream>>>(tmp, part);
  k_bn_fin<<<D_, 256, 0, stream>>>(part, agg_bn_g, agg_bn_b, scaleb, shiftb);
  k_mfma_af32<true, true><<<dim3(GM, 2), 256, 0, stream>>>(
      tmp, D_, D_, cw0_h, cw0_l, ent, N_ENT, D_, KP_D, (long)D_,
      scaleb, shiftb, concat_b);
  k_colstats<<<GSTAT2, 64, 0, stream>>>(ent, part);
  k_bn_fin<<<D_, 256, 0, stream>>>(part, cell_bn_g, cell_bn_b, scaleb, shiftb);
  // cell-BN0 not materialized: fused into layer-1 aggregate's gather
  k_gemm_abt<8, 4><<<dim3(4, 4), 256, 0, stream>>>(relA, wrT, relB, NREL_, D_, D_,
                                                   (long)D_);

  // ================= layer 1 =================
  k_aggregate<true><<<GA, 256, 0, stream>>>(ent, relB, row_ptr, counts,
                                            csr_src, csr_et, tmp, scaleb, shiftb);
  k_colstats<<<GSTAT2, 64, 0, stream>>>(tmp, part);
  k_bn_fin<<<D_, 256, 0, stream>>>(part, agg_bn_g + D_, agg_bn_b + D_, scaleb, shiftb);
  k_mfma_af32<true, true><<<dim3(GM, 2), 256, 0, stream>>>(
      tmp, D_, D_, cw1_h, cw1_l, ent, N_ENT, D_, KP_D, (long)D_,
      scaleb, shiftb, concat_b + D_);
  k_colstats<<<GSTAT2, 64, 0, stream>>>(ent, part);
  k_bn_fin<<<D_, 256, 0, stream>>>(part, cell_bn_g + D_, cell_bn_b + D_, scaleb, shiftb);
  k_norm_split<<<2048, 256, 0, stream>>>(ent, scaleb, shiftb, ent_h, ent_l);
  k_gemm_abt<8, 4><<<dim3(4, 4), 256, 0, stream>>>(relB, wrT, relA, NREL_, D_, D_,
                                                   (long)D_);

  // ---- score operands ----
  k_qsplit<<<(B_ * KP_D + 255) / 256, 256, 0, stream>>>(ent, relA, subj, rel,
                                                        q_h, q_l);

  // ---- DistMult score: r10 config (3-term, temporal stores, 2 blocks/CU) ----
  k_score4<<<dim3(8 * 1563), 256, 0, stream>>>(q_h, q_l, ent_h, ent_l, out);
}